// Round 1
// baseline (2228.114 us; speedup 1.0000x reference)
//
#include <hip/hip_runtime.h>

#define NPTS 500000
#define NVOX 50000

typedef unsigned short u16;
typedef unsigned int u32;
typedef __attribute__((ext_vector_type(8))) short short8;
typedef __attribute__((ext_vector_type(4))) float floatx4;
typedef __attribute__((ext_vector_type(4))) unsigned int uintx4;

__device__ __forceinline__ u16 f2bf(float f) {
    u32 u = __float_as_uint(f);
    u = u + 0x7fffu + ((u >> 16) & 1u);   // RNE
    return (u16)(u >> 16);
}

// ---- K0: swizzle fp32 weight (K x N, row-major) into B-fragment-contiguous bf16 ----
// B-frag for mfma_f32_16x16x32_bf16: lane l holds B[kk*32 + q*8 + j][n], q=l>>4, n=base+(l&15).
// Layout: Wf[((kk*4+q)*N + n)*8 + j]  -> each lane reads 16B contiguous.
__global__ void k_wtransform(const float* __restrict__ W, u16* __restrict__ Wf, int K, int N) {
    int t = blockIdx.x * 256 + threadIdx.x;
    if (t >= K * N) return;
    int k = t / N, n = t - k * N;
    int kk = k >> 5, q = (k >> 3) & 3, j = k & 7;
    Wf[((size_t)((kk * 4 + q) * N + n) << 3) + j] = f2bf(W[t]);
}

// ---- K1: fused point feature encoder + attention + segment-max into vox1 ----
__global__ __launch_bounds__(128) void k_pointfeat(
    const float* __restrict__ inp, const int* __restrict__ idx,
    const float* __restrict__ w1x, const float* __restrict__ b1x,
    const float* __restrict__ w2x, const float* __restrict__ b2x,
    const float* __restrict__ w1r, const float* __restrict__ b1r,
    const float* __restrict__ w2r, const float* __restrict__ b2r,
    const float* __restrict__ wax, const float* __restrict__ bax,
    const float* __restrict__ war, const float* __restrict__ bar,
    u16* __restrict__ pf2, float* __restrict__ vox1)
{
    __shared__ float comb[64 * 128];   // [feature][thread], bank-conflict-free
    int t = threadIdx.x;
    int i = blockIdx.x * 128 + t;
    bool act = (i < NPTS);
    float x0 = 0, x1 = 0, x2 = 0, r0 = 0, r1 = 0, r2 = 0;
    if (act) {
        const float* p = inp + (size_t)i * 6;
        x0 = p[0]; x1 = p[1]; x2 = p[2]; r0 = p[3]; r1 = p[4]; r2 = p[5];
    }
    float fx[32], fr[32];
    #pragma unroll
    for (int j = 0; j < 32; j++) { fx[j] = b2x[j]; fr[j] = b2r[j]; }
    // hidden computed on the fly (no 64-reg h array, no runtime register indexing)
    for (int k = 0; k < 64; k++) {
        float hx = fmaxf(b1x[k] + x0 * w1x[k] + x1 * w1x[64 + k] + x2 * w1x[128 + k], 0.f);
        float hr = fmaxf(b1r[k] + r0 * w1r[k] + r1 * w1r[64 + k] + r2 * w1r[128 + k], 0.f);
        #pragma unroll
        for (int j = 0; j < 32; j++) { fx[j] += hx * w2x[k * 32 + j]; fr[j] += hr * w2r[k * 32 + j]; }
    }
    #pragma unroll
    for (int j = 0; j < 32; j++) {
        fx[j] = fmaxf(fx[j], 0.f);
        fr[j] = fmaxf(fr[j], 0.f);
        comb[j * 128 + t] = fx[j];          // own column only, no sync needed
        comb[(32 + j) * 128 + t] = fr[j];
    }
    float ax[32], ar[32];
    #pragma unroll
    for (int j = 0; j < 32; j++) { ax[j] = bax[j]; ar[j] = bar[j]; }
    for (int k = 0; k < 64; k++) {
        float ck = comb[k * 128 + t];       // avoids runtime-indexed register array
        #pragma unroll
        for (int j = 0; j < 32; j++) { ax[j] += ck * wax[k * 32 + j]; ar[j] += ck * war[k * 32 + j]; }
    }
    if (!act) return;
    int v = idx[i];
    u32* dst = (u32*)(pf2 + (size_t)i * 128);
    float* vrow = vox1 + (size_t)v * 128;
    #pragma unroll
    for (int jp = 0; jp < 16; jp++) {
        int j0 = 2 * jp, j1 = 2 * jp + 1;
        float s0 = 1.f / (1.f + __expf(-ax[j0])), s1 = 1.f / (1.f + __expf(-ax[j1]));
        float u0 = 1.f / (1.f + __expf(-ar[j0])), u1 = 1.f / (1.f + __expf(-ar[j1]));
        float a0 = fx[j0], a1 = fx[j1];
        float b0 = fx[j0] * s0, b1 = fx[j1] * s1;
        float c0 = fr[j0], c1 = fr[j1];
        float d0 = fr[j0] * u0, d1 = fr[j1] * u1;
        dst[jp]      = (u32)f2bf(a0) | ((u32)f2bf(a1) << 16);   // ch [0..31]   = fx
        dst[16 + jp] = (u32)f2bf(b0) | ((u32)f2bf(b1) << 16);   // ch [32..63]  = fx*sig
        dst[32 + jp] = (u32)f2bf(c0) | ((u32)f2bf(c1) << 16);   // ch [64..95]  = fr
        dst[48 + jp] = (u32)f2bf(d0) | ((u32)f2bf(d1) << 16);   // ch [96..127] = fr*sig
        // segment max: all values >= 0 -> int bit compare == float compare, init 0 OK
        #pragma unroll
        for (int g = 0; g < 4; g++) {
            float v0g = (g == 0) ? a0 : (g == 1) ? b0 : (g == 2) ? c0 : d0;
            float v1g = (g == 0) ? a1 : (g == 1) ? b1 : (g == 2) ? c1 : d1;
            int* p0 = (int*)(vrow + g * 32 + j0);
            int* p1 = (int*)(vrow + g * 32 + j1);
            int vb0 = __float_as_int(v0g);
            int vb1 = __float_as_int(v1g);
            if (vb0 > *p0) atomicMax(p0, vb0);
            if (vb1 > *p1) atomicMax(p1, vb1);
        }
    }
}

// ---- generic MFMA GEMM: out = relu(A @ W + bias), A fp32 (converted on stage), W pre-swizzled bf16 ----
template<int K, int N, bool OUT_BF16>
__global__ __launch_bounds__(256) void k_gemm_relu(
    const float* __restrict__ A, const u16* __restrict__ Wf,
    const float* __restrict__ bias, void* __restrict__ outp, int M)
{
    constexpr int STRIDE = K + 8;     // +8 bf16 pad: row bank offset 4 -> conflict-free frag reads
    constexpr int TN = N / 64;        // n-tiles per wave
    constexpr int KSTEPS = K / 32;
    constexpr int CW = K / 4;         // floats per staging segment
    __shared__ u16 lds[64 * STRIDE];
    int i0 = blockIdx.x * 64;
    int mcnt = M - i0; if (mcnt > 64) mcnt = 64;
    int t = threadIdx.x;
    {
        int row = t >> 2, cseg = t & 3;
        u16* dst = &lds[row * STRIDE + cseg * CW];
        if (row < mcnt) {
            const float* src = A + (size_t)(i0 + row) * K + cseg * CW;
            #pragma unroll
            for (int c = 0; c < CW / 8; c++) {
                float4 v0 = *(const float4*)(src + c * 8);
                float4 v1 = *(const float4*)(src + c * 8 + 4);
                short8 rr;
                rr[0] = f2bf(v0.x); rr[1] = f2bf(v0.y); rr[2] = f2bf(v0.z); rr[3] = f2bf(v0.w);
                rr[4] = f2bf(v1.x); rr[5] = f2bf(v1.y); rr[6] = f2bf(v1.z); rr[7] = f2bf(v1.w);
                *(short8*)(dst + c * 8) = rr;
            }
        } else {
            short8 z = {0, 0, 0, 0, 0, 0, 0, 0};
            #pragma unroll
            for (int c = 0; c < CW / 8; c++) *(short8*)(dst + c * 8) = z;
        }
    }
    __syncthreads();
    int wave = t >> 6, l = t & 63;
    int q = l >> 4, lm = l & 15;
    int wn0 = wave * (N / 4);
    floatx4 acc[4][TN];
    #pragma unroll
    for (int a = 0; a < 4; a++)
        #pragma unroll
        for (int b = 0; b < TN; b++) acc[a][b] = (floatx4){0.f, 0.f, 0.f, 0.f};
    #pragma unroll
    for (int kk = 0; kk < KSTEPS; kk++) {
        short8 afrag[4], bfrag[TN];
        #pragma unroll
        for (int tm = 0; tm < 4; tm++)
            afrag[tm] = *(const short8*)&lds[(tm * 16 + lm) * STRIDE + kk * 32 + q * 8];
        #pragma unroll
        for (int tn = 0; tn < TN; tn++)
            bfrag[tn] = *(const short8*)&Wf[(size_t)((kk * 4 + q) * N + wn0 + tn * 16 + lm) * 8];
        #pragma unroll
        for (int tm = 0; tm < 4; tm++)
            #pragma unroll
            for (int tn = 0; tn < TN; tn++)
                acc[tm][tn] = __builtin_amdgcn_mfma_f32_16x16x32_bf16(afrag[tm], bfrag[tn], acc[tm][tn], 0, 0, 0);
    }
    #pragma unroll
    for (int tm = 0; tm < 4; tm++)
        #pragma unroll
        for (int tn = 0; tn < TN; tn++) {
            int n = wn0 + tn * 16 + lm;
            float bv = bias[n];
            #pragma unroll
            for (int r = 0; r < 4; r++) {
                int m = tm * 16 + q * 4 + r;   // C/D: row = quad*4+reg, col = lane&15
                if (m < mcnt) {
                    float v = fmaxf(acc[tm][tn][r] + bv, 0.f);
                    if (OUT_BF16) ((u16*)outp)[(size_t)(i0 + m) * N + n] = f2bf(v);
                    else          ((float*)outp)[(size_t)(i0 + m) * N + n] = v;
                }
            }
        }
}

// ---- K3: fused pf3 = [voxf[idx], pf2]; pf5 = relu(relu(pf3@w3+b3)@w4+b4); segment-max into vox2 ----
__global__ __launch_bounds__(256) void k_pointmlp(
    const u16* __restrict__ voxf, const u16* __restrict__ pf2, const int* __restrict__ idx,
    const u16* __restrict__ w3f, const float* __restrict__ b3,
    const u16* __restrict__ w4f, const float* __restrict__ b4,
    float* __restrict__ vox2)
{
    constexpr int STRIDE = 264;
    __shared__ u16 lds[64 * STRIDE];
    __shared__ int lvid[64];
    int i0 = blockIdx.x * 64;
    int mcnt = NPTS - i0; if (mcnt > 64) mcnt = 64;
    int t = threadIdx.x;
    if (t < 64) lvid[t] = (t < mcnt) ? idx[i0 + t] : 0;
    {
        int row = t >> 2, cseg = t & 3;       // 4 threads/row, 64 bf16 each
        u16* dst = &lds[row * STRIDE + cseg * 64];
        if (row < mcnt) {
            const u16* src;
            if (cseg < 2) src = voxf + (size_t)idx[i0 + row] * 128 + cseg * 64;       // pg half
            else          src = pf2 + (size_t)(i0 + row) * 128 + (cseg - 2) * 64;     // pf2 half
            #pragma unroll
            for (int c = 0; c < 8; c++)
                *(uintx4*)(dst + c * 8) = *(const uintx4*)(src + c * 8);
        } else {
            uintx4 z = {0, 0, 0, 0};
            #pragma unroll
            for (int c = 0; c < 8; c++) *(uintx4*)(dst + c * 8) = z;
        }
    }
    __syncthreads();
    int wave = t >> 6, l = t & 63;
    int q = l >> 4, lm = l & 15;
    int wn0 = wave * 64;
    floatx4 acc[4][4];
    #pragma unroll
    for (int a = 0; a < 4; a++)
        #pragma unroll
        for (int b = 0; b < 4; b++) acc[a][b] = (floatx4){0.f, 0.f, 0.f, 0.f};
    #pragma unroll
    for (int kk = 0; kk < 8; kk++) {
        short8 afrag[4], bfrag[4];
        #pragma unroll
        for (int tm = 0; tm < 4; tm++)
            afrag[tm] = *(const short8*)&lds[(tm * 16 + lm) * STRIDE + kk * 32 + q * 8];
        #pragma unroll
        for (int tn = 0; tn < 4; tn++)
            bfrag[tn] = *(const short8*)&w3f[(size_t)((kk * 4 + q) * 256 + wn0 + tn * 16 + lm) * 8];
        #pragma unroll
        for (int tm = 0; tm < 4; tm++)
            #pragma unroll
            for (int tn = 0; tn < 4; tn++)
                acc[tm][tn] = __builtin_amdgcn_mfma_f32_16x16x32_bf16(afrag[tm], bfrag[tn], acc[tm][tn], 0, 0, 0);
    }
    __syncthreads();   // all waves done reading A-tile
    // H = relu(acc + b3) -> LDS bf16 (each wave owns its column range, rows 0..63)
    #pragma unroll
    for (int tm = 0; tm < 4; tm++)
        #pragma unroll
        for (int tn = 0; tn < 4; tn++) {
            int n = wn0 + tn * 16 + lm;
            float bv = b3[n];
            #pragma unroll
            for (int r = 0; r < 4; r++) {
                int m = tm * 16 + q * 4 + r;
                lds[m * STRIDE + n] = f2bf(fmaxf(acc[tm][tn][r] + bv, 0.f));
            }
        }
    __syncthreads();
    floatx4 acc2[4][4];
    #pragma unroll
    for (int a = 0; a < 4; a++)
        #pragma unroll
        for (int b = 0; b < 4; b++) acc2[a][b] = (floatx4){0.f, 0.f, 0.f, 0.f};
    #pragma unroll
    for (int kk = 0; kk < 8; kk++) {
        short8 afrag[4], bfrag[4];
        #pragma unroll
        for (int tm = 0; tm < 4; tm++)
            afrag[tm] = *(const short8*)&lds[(tm * 16 + lm) * STRIDE + kk * 32 + q * 8];
        #pragma unroll
        for (int tn = 0; tn < 4; tn++)
            bfrag[tn] = *(const short8*)&w4f[(size_t)((kk * 4 + q) * 256 + wn0 + tn * 16 + lm) * 8];
        #pragma unroll
        for (int tm = 0; tm < 4; tm++)
            #pragma unroll
            for (int tn = 0; tn < 4; tn++)
                acc2[tm][tn] = __builtin_amdgcn_mfma_f32_16x16x32_bf16(afrag[tm], bfrag[tn], acc2[tm][tn], 0, 0, 0);
    }
    // epilogue: bias + relu + segment-max (values >= 0, int compare)
    #pragma unroll
    for (int tm = 0; tm < 4; tm++)
        #pragma unroll
        for (int tn = 0; tn < 4; tn++) {
            int n = wn0 + tn * 16 + lm;
            float bv = b4[n];
            #pragma unroll
            for (int r = 0; r < 4; r++) {
                int m = tm * 16 + q * 4 + r;
                if (m < mcnt) {
                    float v = fmaxf(acc2[tm][tn][r] + bv, 0.f);
                    int vb = __float_as_int(v);
                    int* addr = (int*)(vox2 + (size_t)lvid[m] * 256 + n);
                    if (vb > *addr) atomicMax(addr, vb);
                }
            }
        }
}

extern "C" void kernel_launch(void* const* d_in, const int* in_sizes, int n_in,
                              void* d_out, int out_size, void* d_ws, size_t ws_size,
                              hipStream_t stream) {
    const float* inp = (const float*)d_in[0];
    const int*   idx = (const int*)d_in[1];
    // d_in[2] = num_vox (known statically = 50000)
    const float* w1x = (const float*)d_in[3];  const float* b1x = (const float*)d_in[4];
    const float* w2x = (const float*)d_in[5];  const float* b2x = (const float*)d_in[6];
    const float* w1r = (const float*)d_in[7];  const float* b1r = (const float*)d_in[8];
    const float* w2r = (const float*)d_in[9];  const float* b2r = (const float*)d_in[10];
    const float* wax = (const float*)d_in[11]; const float* bax = (const float*)d_in[12];
    const float* war = (const float*)d_in[13]; const float* bar = (const float*)d_in[14];
    const float* wv1 = (const float*)d_in[15]; const float* bv1 = (const float*)d_in[16];
    const float* w3  = (const float*)d_in[17]; const float* b3  = (const float*)d_in[18];
    const float* w4  = (const float*)d_in[19]; const float* b4  = (const float*)d_in[20];
    const float* wv2 = (const float*)d_in[21]; const float* bv2 = (const float*)d_in[22];
    float* out = (float*)d_out;

    char* ws = (char*)d_ws;
    u16*   pf2  = (u16*)ws;   ws += (size_t)NPTS * 128 * sizeof(u16);   // 128 MB
    float* vox1 = (float*)ws; ws += (size_t)NVOX * 128 * sizeof(float); // 25.6 MB
    u16*   voxf = (u16*)ws;   ws += (size_t)NVOX * 128 * sizeof(u16);   // 12.8 MB
    float* vox2 = (float*)ws; ws += (size_t)NVOX * 256 * sizeof(float); // 51.2 MB
    u16*   w3f  = (u16*)ws;   ws += 65536 * sizeof(u16);
    u16*   w4f  = (u16*)ws;   ws += 65536 * sizeof(u16);
    u16*   wv1f = (u16*)ws;   ws += 16384 * sizeof(u16);
    u16*   wv2f = (u16*)ws;   ws += 65536 * sizeof(u16);

    hipMemsetAsync(vox1, 0, (size_t)NVOX * 128 * sizeof(float), stream);
    hipMemsetAsync(vox2, 0, (size_t)NVOX * 256 * sizeof(float), stream);

    k_wtransform<<<256, 256, 0, stream>>>(w3, w3f, 256, 256);
    k_wtransform<<<256, 256, 0, stream>>>(w4, w4f, 256, 256);
    k_wtransform<<<64,  256, 0, stream>>>(wv1, wv1f, 128, 128);
    k_wtransform<<<256, 256, 0, stream>>>(wv2, wv2f, 256, 256);

    k_pointfeat<<<(NPTS + 127) / 128, 128, 0, stream>>>(
        inp, idx, w1x, b1x, w2x, b2x, w1r, b1r, w2r, b2r, wax, bax, war, bar, pf2, vox1);

    k_gemm_relu<128, 128, true><<<(NVOX + 63) / 64, 256, 0, stream>>>(vox1, wv1f, bv1, (void*)voxf, NVOX);

    k_pointmlp<<<(NPTS + 63) / 64, 256, 0, stream>>>(voxf, pf2, idx, w3f, b3, w4f, b4, vox2);

    k_gemm_relu<256, 256, false><<<(NVOX + 63) / 64, 256, 0, stream>>>(vox2, wv2f, bv2, (void*)out, NVOX);
}

// Round 2
// 982.572 us; speedup vs baseline: 2.2676x; 2.2676x over previous
//
#include <hip/hip_runtime.h>

#define NPTS 500000
#define NVOX 50000

typedef unsigned short u16;
typedef unsigned int u32;
typedef __attribute__((ext_vector_type(8))) short short8;
typedef __attribute__((ext_vector_type(4))) float floatx4;
typedef __attribute__((ext_vector_type(4))) unsigned int uintx4;

__device__ __forceinline__ u16 f2bf(float f) {
    u32 u = __float_as_uint(f);
    u = u + 0x7fffu + ((u >> 16) & 1u);   // RNE
    return (u16)(u >> 16);
}

// ---- K0: swizzle fp32 weight (K x N, row-major) into B-fragment-contiguous bf16 ----
// B-frag for mfma_f32_16x16x32_bf16: lane l holds B[kk*32 + q*8 + j][n], q=l>>4, n=base+(l&15).
// Layout: Wf[((kk*4+q)*N + n)*8 + j]  -> each lane reads 16B contiguous.
__global__ void k_wtransform(const float* __restrict__ W, u16* __restrict__ Wf, int K, int N) {
    int t = blockIdx.x * 256 + threadIdx.x;
    if (t >= K * N) return;
    int k = t / N, n = t - k * N;
    int kk = k >> 5, q = (k >> 3) & 3, j = k & 7;
    Wf[((size_t)((kk * 4 + q) * N + n) << 3) + j] = f2bf(W[t]);
}

// block-diag [[w2x,0],[0,w2r]] (128x64), swizzled
__global__ void k_wcat(const float* __restrict__ w2x, const float* __restrict__ w2r, u16* __restrict__ wcatf) {
    int t = blockIdx.x * 256 + threadIdx.x;
    if (t >= 128 * 64) return;
    int k = t >> 6, n = t & 63;
    float v;
    if (k < 64) v = (n < 32) ? w2x[k * 32 + n] : 0.f;
    else        v = (n >= 32) ? w2r[(k - 64) * 32 + (n - 32)] : 0.f;
    int kk = k >> 5, q = (k >> 3) & 3, j = k & 7;
    wcatf[((size_t)((kk * 4 + q) * 64 + n) << 3) + j] = f2bf(v);
}

// [wax | war] (64x64), swizzled
__global__ void k_watt(const float* __restrict__ wax, const float* __restrict__ war, u16* __restrict__ wattf) {
    int t = blockIdx.x * 256 + threadIdx.x;
    if (t >= 64 * 64) return;
    int k = t >> 6, n = t & 63;
    float v = (n < 32) ? wax[k * 32 + n] : war[k * 32 + (n - 32)];
    int kk = k >> 5, q = (k >> 3) & 3, j = k & 7;
    wattf[((size_t)((kk * 4 + q) * 64 + n) << 3) + j] = f2bf(v);
}

// ---- K1: MFMA point feature encoder: 64 points/block, writes pf2 bf16 (no atomics) ----
__global__ __launch_bounds__(256) void k_pointfeat(
    const float* __restrict__ inp,
    const float* __restrict__ w1x, const float* __restrict__ b1x,
    const float* __restrict__ w1r, const float* __restrict__ b1r,
    const u16* __restrict__ wcatf, const float* __restrict__ b2x, const float* __restrict__ b2r,
    const u16* __restrict__ wattf, const float* __restrict__ bax, const float* __restrict__ bar,
    u16* __restrict__ pf2)
{
    __shared__ u16 hbuf[64 * 136];   // h tile (64x128 +8 pad); reused for pf2 out-tile
    __shared__ u16 cbuf[64 * 72];    // comb tile (64x64 +8 pad)
    __shared__ float wl[512];        // w1x(192) b1x(64) w1r(192) b1r(64)
    int t = threadIdx.x;
    int i0 = blockIdx.x * 64;
    for (int s = t; s < 512; s += 256) {
        float v;
        if (s < 192)      v = w1x[s];
        else if (s < 256) v = b1x[s - 192];
        else if (s < 448) v = w1r[s - 256];
        else              v = b1r[s - 448];
        wl[s] = v;
    }
    __syncthreads();
    {   // layer 1: K=3 on VALU, 4 threads/point each produce 16 h_x + 16 h_r cols
        int m = t >> 2, c = t & 3;
        int i = i0 + m;
        float x0 = 0, x1 = 0, x2 = 0, r0 = 0, r1 = 0, r2 = 0;
        if (i < NPTS) {
            const float* p = inp + (size_t)i * 6;
            x0 = p[0]; x1 = p[1]; x2 = p[2]; r0 = p[3]; r1 = p[4]; r2 = p[5];
        }
        u16* hb = &hbuf[m * 136 + c * 16];
        #pragma unroll
        for (int jp = 0; jp < 8; jp++) {
            int c0 = c * 16 + 2 * jp, c1 = c0 + 1;
            float hx0 = fmaxf(wl[192 + c0] + x0 * wl[c0] + x1 * wl[64 + c0] + x2 * wl[128 + c0], 0.f);
            float hx1 = fmaxf(wl[192 + c1] + x0 * wl[c1] + x1 * wl[64 + c1] + x2 * wl[128 + c1], 0.f);
            float hr0 = fmaxf(wl[448 + c0] + r0 * wl[256 + c0] + r1 * wl[320 + c0] + r2 * wl[384 + c0], 0.f);
            float hr1 = fmaxf(wl[448 + c1] + r0 * wl[256 + c1] + r1 * wl[320 + c1] + r2 * wl[384 + c1], 0.f);
            *(u32*)(hb + 2 * jp)      = (u32)f2bf(hx0) | ((u32)f2bf(hx1) << 16);
            *(u32*)(hb + 64 + 2 * jp) = (u32)f2bf(hr0) | ((u32)f2bf(hr1) << 16);
        }
    }
    __syncthreads();
    int wave = t >> 6, l = t & 63, q = l >> 4, lm = l & 15;
    int n = wave * 16 + lm;    // each wave owns 16 output cols
    // GEMM1: comb(64x64) = h(64x128) @ wcat(128x64)
    floatx4 acc[4];
    #pragma unroll
    for (int a = 0; a < 4; a++) acc[a] = (floatx4){0.f, 0.f, 0.f, 0.f};
    #pragma unroll
    for (int kk = 0; kk < 4; kk++) {
        short8 bfrag = *(const short8*)&wcatf[(size_t)((kk * 4 + q) * 64 + n) << 3];
        #pragma unroll
        for (int tm = 0; tm < 4; tm++) {
            short8 afrag = *(const short8*)&hbuf[(tm * 16 + lm) * 136 + kk * 32 + q * 8];
            acc[tm] = __builtin_amdgcn_mfma_f32_16x16x32_bf16(afrag, bfrag, acc[tm], 0, 0, 0);
        }
    }
    float bv = (n < 32) ? b2x[n] : b2r[n - 32];
    float comb_keep[4][4];
    #pragma unroll
    for (int tm = 0; tm < 4; tm++)
        #pragma unroll
        for (int r = 0; r < 4; r++) {
            float v = fmaxf(acc[tm][r] + bv, 0.f);
            comb_keep[tm][r] = v;
            int m = tm * 16 + q * 4 + r;     // C/D: row = quad*4+reg, col = lane&15
            cbuf[m * 72 + n] = f2bf(v);
        }
    __syncthreads();
    // GEMM2: att(64x64) = comb(64x64) @ watt(64x64); same C-layout as comb -> register-local gating
    floatx4 acc2[4];
    #pragma unroll
    for (int a = 0; a < 4; a++) acc2[a] = (floatx4){0.f, 0.f, 0.f, 0.f};
    #pragma unroll
    for (int kk = 0; kk < 2; kk++) {
        short8 bfrag = *(const short8*)&wattf[(size_t)((kk * 4 + q) * 64 + n) << 3];
        #pragma unroll
        for (int tm = 0; tm < 4; tm++) {
            short8 afrag = *(const short8*)&cbuf[(tm * 16 + lm) * 72 + kk * 32 + q * 8];
            acc2[tm] = __builtin_amdgcn_mfma_f32_16x16x32_bf16(afrag, bfrag, acc2[tm], 0, 0, 0);
        }
    }
    float bv2 = (n < 32) ? bax[n] : bar[n - 32];
    int pp = (n < 32) ? n : 32 + n;   // pf2 col of plain value; gated at pp+32
    #pragma unroll
    for (int tm = 0; tm < 4; tm++)
        #pragma unroll
        for (int r = 0; r < 4; r++) {
            float att = acc2[tm][r] + bv2;
            float sg = 1.f / (1.f + __expf(-att));
            float plain = comb_keep[tm][r];
            float gated = plain * sg;
            int m = tm * 16 + q * 4 + r;
            hbuf[m * 136 + pp] = f2bf(plain);       // hbuf reads all finished before prev barrier
            hbuf[m * 136 + pp + 32] = f2bf(gated);
        }
    __syncthreads();
    {   // coalesced pf2 store: 4 threads/row x 64B
        int row = t >> 2, seg = t & 3;
        if (i0 + row < NPTS) {
            const u16* src = &hbuf[row * 136 + seg * 32];
            u16* dst = pf2 + (size_t)(i0 + row) * 128 + seg * 32;
            *(uintx4*)dst = *(const uintx4*)src;
            *(uintx4*)(dst + 8) = *(const uintx4*)(src + 8);
        }
    }
}

// ---- CSR build: histogram -> scan -> scatter ----
__global__ void k_hist(const int* __restrict__ idx, int* __restrict__ hcnt) {
    int i = blockIdx.x * 256 + threadIdx.x;
    if (i < NPTS) atomicAdd(&hcnt[idx[i]], 1);
}

__global__ __launch_bounds__(256) void k_scan(const int* __restrict__ hcnt,
                                              int* __restrict__ start, int* __restrict__ cur) {
    __shared__ int wsum[4];
    int t = threadIdx.x;
    int lane = t & 63, w = t >> 6;
    int running = 0;
    for (int base = 0; base < NVOX; base += 256) {
        int c = (base + t < NVOX) ? hcnt[base + t] : 0;
        int v = c;
        #pragma unroll
        for (int d = 1; d < 64; d <<= 1) {
            int o = __shfl_up(v, d, 64);
            if (lane >= d) v += o;
        }
        if (lane == 63) wsum[w] = v;
        __syncthreads();
        int wo = 0;
        #pragma unroll
        for (int k = 0; k < 4; k++) if (k < w) wo += wsum[k];
        int excl = running + wo + v - c;
        if (base + t < NVOX) { start[base + t] = excl; cur[base + t] = excl; }
        running += wsum[0] + wsum[1] + wsum[2] + wsum[3];
        __syncthreads();
    }
}

__global__ void k_scatter(const int* __restrict__ idx, int* __restrict__ cur, int* __restrict__ plist) {
    int i = blockIdx.x * 256 + threadIdx.x;
    if (i < NPTS) {
        int pos = atomicAdd(&cur[idx[i]], 1);
        plist[pos] = i;
    }
}

// ---- segment-max over pf2 rows (bf16 bit-compare: all values >= 0) ----
__global__ __launch_bounds__(256) void k_segmax(
    const u16* __restrict__ pf2, const int* __restrict__ plist,
    const int* __restrict__ start, const int* __restrict__ hcnt,
    u16* __restrict__ voxmax)
{
    int w = threadIdx.x >> 6, l = threadIdx.x & 63;
    int v = blockIdx.x * 4 + w;
    if (v >= NVOX) return;
    int s = start[v], c = hcnt[v];
    u32 mlo = 0, mhi = 0;
    for (int e = 0; e < c; e++) {
        int p = plist[s + e];
        u32 u = *(const u32*)&pf2[(size_t)p * 128 + 2 * l];
        u32 lo = u & 0xffffu, hi = u >> 16;
        mlo = lo > mlo ? lo : mlo;
        mhi = hi > mhi ? hi : mhi;
    }
    ((u32*)voxmax)[(size_t)v * 64 + l] = mlo | (mhi << 16);
}

// ---- generic MFMA GEMM: out = relu(A @ W + bias); A fp32 or bf16; W pre-swizzled bf16 ----
template<int K, int N, bool ABF16, bool OUT_BF16>
__global__ __launch_bounds__(256) void k_gemm_relu(
    const void* __restrict__ Ap, const u16* __restrict__ Wf,
    const float* __restrict__ bias, void* __restrict__ outp, int M)
{
    constexpr int STRIDE = K + 8;
    constexpr int TN = N / 64;
    constexpr int KSTEPS = K / 32;
    constexpr int CW = K / 4;         // elems per staging segment
    __shared__ u16 lds[64 * STRIDE];
    int i0 = blockIdx.x * 64;
    int mcnt = M - i0; if (mcnt > 64) mcnt = 64;
    int t = threadIdx.x;
    {
        int row = t >> 2, cseg = t & 3;
        u16* dst = &lds[row * STRIDE + cseg * CW];
        if (row < mcnt) {
            if (ABF16) {
                const u16* src = (const u16*)Ap + (size_t)(i0 + row) * K + cseg * CW;
                #pragma unroll
                for (int c = 0; c < CW / 8; c++)
                    *(uintx4*)(dst + c * 8) = *(const uintx4*)(src + c * 8);
            } else {
                const float* src = (const float*)Ap + (size_t)(i0 + row) * K + cseg * CW;
                #pragma unroll
                for (int c = 0; c < CW / 8; c++) {
                    float4 v0 = *(const float4*)(src + c * 8);
                    float4 v1 = *(const float4*)(src + c * 8 + 4);
                    short8 rr;
                    rr[0] = f2bf(v0.x); rr[1] = f2bf(v0.y); rr[2] = f2bf(v0.z); rr[3] = f2bf(v0.w);
                    rr[4] = f2bf(v1.x); rr[5] = f2bf(v1.y); rr[6] = f2bf(v1.z); rr[7] = f2bf(v1.w);
                    *(short8*)(dst + c * 8) = rr;
                }
            }
        } else {
            short8 z = {0, 0, 0, 0, 0, 0, 0, 0};
            #pragma unroll
            for (int c = 0; c < CW / 8; c++) *(short8*)(dst + c * 8) = z;
        }
    }
    __syncthreads();
    int wave = t >> 6, l = t & 63;
    int q = l >> 4, lm = l & 15;
    int wn0 = wave * (N / 4);
    floatx4 acc[4][TN];
    #pragma unroll
    for (int a = 0; a < 4; a++)
        #pragma unroll
        for (int b = 0; b < TN; b++) acc[a][b] = (floatx4){0.f, 0.f, 0.f, 0.f};
    #pragma unroll
    for (int kk = 0; kk < KSTEPS; kk++) {
        short8 afrag[4], bfrag[TN];
        #pragma unroll
        for (int tm = 0; tm < 4; tm++)
            afrag[tm] = *(const short8*)&lds[(tm * 16 + lm) * STRIDE + kk * 32 + q * 8];
        #pragma unroll
        for (int tn = 0; tn < TN; tn++)
            bfrag[tn] = *(const short8*)&Wf[(size_t)((kk * 4 + q) * N + wn0 + tn * 16 + lm) * 8];
        #pragma unroll
        for (int tm = 0; tm < 4; tm++)
            #pragma unroll
            for (int tn = 0; tn < TN; tn++)
                acc[tm][tn] = __builtin_amdgcn_mfma_f32_16x16x32_bf16(afrag[tm], bfrag[tn], acc[tm][tn], 0, 0, 0);
    }
    #pragma unroll
    for (int tm = 0; tm < 4; tm++)
        #pragma unroll
        for (int tn = 0; tn < TN; tn++) {
            int n = wn0 + tn * 16 + lm;
            float bv = bias[n];
            #pragma unroll
            for (int r = 0; r < 4; r++) {
                int m = tm * 16 + q * 4 + r;
                if (m < mcnt) {
                    float v = fmaxf(acc[tm][tn][r] + bv, 0.f);
                    if (OUT_BF16) ((u16*)outp)[(size_t)(i0 + m) * N + n] = f2bf(v);
                    else          ((float*)outp)[(size_t)(i0 + m) * N + n] = v;
                }
            }
        }
}

// ---- K3: fused pf3 = [voxf[idx], pf2]; pf5 = relu(relu(pf3@w3+b3)@w4+b4); segment-max into vox2 ----
__global__ __launch_bounds__(256) void k_pointmlp(
    const u16* __restrict__ voxf, const u16* __restrict__ pf2, const int* __restrict__ idx,
    const u16* __restrict__ w3f, const float* __restrict__ b3,
    const u16* __restrict__ w4f, const float* __restrict__ b4,
    float* __restrict__ vox2)
{
    constexpr int STRIDE = 264;
    __shared__ u16 lds[64 * STRIDE];
    __shared__ int lvid[64];
    int i0 = blockIdx.x * 64;
    int mcnt = NPTS - i0; if (mcnt > 64) mcnt = 64;
    int t = threadIdx.x;
    if (t < 64) lvid[t] = (t < mcnt) ? idx[i0 + t] : 0;
    {
        int row = t >> 2, cseg = t & 3;
        u16* dst = &lds[row * STRIDE + cseg * 64];
        if (row < mcnt) {
            const u16* src;
            if (cseg < 2) src = voxf + (size_t)idx[i0 + row] * 128 + cseg * 64;
            else          src = pf2 + (size_t)(i0 + row) * 128 + (cseg - 2) * 64;
            #pragma unroll
            for (int c = 0; c < 8; c++)
                *(uintx4*)(dst + c * 8) = *(const uintx4*)(src + c * 8);
        } else {
            uintx4 z = {0, 0, 0, 0};
            #pragma unroll
            for (int c = 0; c < 8; c++) *(uintx4*)(dst + c * 8) = z;
        }
    }
    __syncthreads();
    int wave = t >> 6, l = t & 63;
    int q = l >> 4, lm = l & 15;
    int wn0 = wave * 64;
    floatx4 acc[4][4];
    #pragma unroll
    for (int a = 0; a < 4; a++)
        #pragma unroll
        for (int b = 0; b < 4; b++) acc[a][b] = (floatx4){0.f, 0.f, 0.f, 0.f};
    #pragma unroll
    for (int kk = 0; kk < 8; kk++) {
        short8 afrag[4], bfrag[4];
        #pragma unroll
        for (int tm = 0; tm < 4; tm++)
            afrag[tm] = *(const short8*)&lds[(tm * 16 + lm) * STRIDE + kk * 32 + q * 8];
        #pragma unroll
        for (int tn = 0; tn < 4; tn++)
            bfrag[tn] = *(const short8*)&w3f[(size_t)((kk * 4 + q) * 256 + wn0 + tn * 16 + lm) * 8];
        #pragma unroll
        for (int tm = 0; tm < 4; tm++)
            #pragma unroll
            for (int tn = 0; tn < 4; tn++)
                acc[tm][tn] = __builtin_amdgcn_mfma_f32_16x16x32_bf16(afrag[tm], bfrag[tn], acc[tm][tn], 0, 0, 0);
    }
    __syncthreads();
    #pragma unroll
    for (int tm = 0; tm < 4; tm++)
        #pragma unroll
        for (int tn = 0; tn < 4; tn++) {
            int n = wn0 + tn * 16 + lm;
            float bv = b3[n];
            #pragma unroll
            for (int r = 0; r < 4; r++) {
                int m = tm * 16 + q * 4 + r;
                lds[m * STRIDE + n] = f2bf(fmaxf(acc[tm][tn][r] + bv, 0.f));
            }
        }
    __syncthreads();
    floatx4 acc2[4][4];
    #pragma unroll
    for (int a = 0; a < 4; a++)
        #pragma unroll
        for (int b = 0; b < 4; b++) acc2[a][b] = (floatx4){0.f, 0.f, 0.f, 0.f};
    #pragma unroll
    for (int kk = 0; kk < 8; kk++) {
        short8 afrag[4], bfrag[4];
        #pragma unroll
        for (int tm = 0; tm < 4; tm++)
            afrag[tm] = *(const short8*)&lds[(tm * 16 + lm) * STRIDE + kk * 32 + q * 8];
        #pragma unroll
        for (int tn = 0; tn < 4; tn++)
            bfrag[tn] = *(const short8*)&w4f[(size_t)((kk * 4 + q) * 256 + wn0 + tn * 16 + lm) * 8];
        #pragma unroll
        for (int tm = 0; tm < 4; tm++)
            #pragma unroll
            for (int tn = 0; tn < 4; tn++)
                acc2[tm][tn] = __builtin_amdgcn_mfma_f32_16x16x32_bf16(afrag[tm], bfrag[tn], acc2[tm][tn], 0, 0, 0);
    }
    #pragma unroll
    for (int tm = 0; tm < 4; tm++)
        #pragma unroll
        for (int tn = 0; tn < 4; tn++) {
            int n = wn0 + tn * 16 + lm;
            float bv = b4[n];
            #pragma unroll
            for (int r = 0; r < 4; r++) {
                int m = tm * 16 + q * 4 + r;
                if (m < mcnt) {
                    float v = fmaxf(acc2[tm][tn][r] + bv, 0.f);
                    int vb = __float_as_int(v);
                    int* addr = (int*)(vox2 + (size_t)lvid[m] * 256 + n);
                    if (vb > *addr) atomicMax(addr, vb);
                }
            }
        }
}

extern "C" void kernel_launch(void* const* d_in, const int* in_sizes, int n_in,
                              void* d_out, int out_size, void* d_ws, size_t ws_size,
                              hipStream_t stream) {
    const float* inp = (const float*)d_in[0];
    const int*   idx = (const int*)d_in[1];
    const float* w1x = (const float*)d_in[3];  const float* b1x = (const float*)d_in[4];
    const float* w2x = (const float*)d_in[5];  const float* b2x = (const float*)d_in[6];
    const float* w1r = (const float*)d_in[7];  const float* b1r = (const float*)d_in[8];
    const float* w2r = (const float*)d_in[9];  const float* b2r = (const float*)d_in[10];
    const float* wax = (const float*)d_in[11]; const float* bax = (const float*)d_in[12];
    const float* war = (const float*)d_in[13]; const float* bar = (const float*)d_in[14];
    const float* wv1 = (const float*)d_in[15]; const float* bv1 = (const float*)d_in[16];
    const float* w3  = (const float*)d_in[17]; const float* b3  = (const float*)d_in[18];
    const float* w4  = (const float*)d_in[19]; const float* b4  = (const float*)d_in[20];
    const float* wv2 = (const float*)d_in[21]; const float* bv2 = (const float*)d_in[22];
    float* out = (float*)d_out;

    char* ws = (char*)d_ws;
    u16*   pf2    = (u16*)ws;   ws += (size_t)NPTS * 128 * sizeof(u16);   // 128 MB
    u16*   voxmax = (u16*)ws;   ws += (size_t)NVOX * 128 * sizeof(u16);   // 12.8 MB
    u16*   voxf   = (u16*)ws;   ws += (size_t)NVOX * 128 * sizeof(u16);   // 12.8 MB
    float* vox2   = (float*)ws; ws += (size_t)NVOX * 256 * sizeof(float); // 51.2 MB
    u16*   w3f    = (u16*)ws;   ws += 65536 * sizeof(u16);
    u16*   w4f    = (u16*)ws;   ws += 65536 * sizeof(u16);
    u16*   wv1f   = (u16*)ws;   ws += 16384 * sizeof(u16);
    u16*   wv2f   = (u16*)ws;   ws += 65536 * sizeof(u16);
    u16*   wcatf  = (u16*)ws;   ws += 8192 * sizeof(u16);
    u16*   wattf  = (u16*)ws;   ws += 4096 * sizeof(u16);
    int*   hcnt   = (int*)ws;   ws += (size_t)NVOX * sizeof(int);
    int*   start  = (int*)ws;   ws += (size_t)NVOX * sizeof(int);
    int*   cur    = (int*)ws;   ws += (size_t)NVOX * sizeof(int);
    int*   plist  = (int*)ws;   ws += (size_t)NPTS * sizeof(int);

    hipMemsetAsync(hcnt, 0, (size_t)NVOX * sizeof(int), stream);
    hipMemsetAsync(vox2, 0, (size_t)NVOX * 256 * sizeof(float), stream);

    k_wtransform<<<256, 256, 0, stream>>>(w3, w3f, 256, 256);
    k_wtransform<<<256, 256, 0, stream>>>(w4, w4f, 256, 256);
    k_wtransform<<<64,  256, 0, stream>>>(wv1, wv1f, 128, 128);
    k_wtransform<<<256, 256, 0, stream>>>(wv2, wv2f, 256, 256);
    k_wcat<<<32, 256, 0, stream>>>(w2x, w2r, wcatf);
    k_watt<<<16, 256, 0, stream>>>(wax, war, wattf);

    k_hist<<<(NPTS + 255) / 256, 256, 0, stream>>>(idx, hcnt);
    k_scan<<<1, 256, 0, stream>>>(hcnt, start, cur);
    k_scatter<<<(NPTS + 255) / 256, 256, 0, stream>>>(idx, cur, plist);

    k_pointfeat<<<(NPTS + 63) / 64, 256, 0, stream>>>(
        inp, w1x, b1x, w1r, b1r, wcatf, b2x, b2r, wattf, bax, bar, pf2);

    k_segmax<<<(NVOX + 3) / 4, 256, 0, stream>>>(pf2, plist, start, hcnt, voxmax);

    k_gemm_relu<128, 128, true, true><<<(NVOX + 63) / 64, 256, 0, stream>>>(
        (const void*)voxmax, wv1f, bv1, (void*)voxf, NVOX);

    k_pointmlp<<<(NPTS + 63) / 64, 256, 0, stream>>>(voxf, pf2, idx, w3f, b3, w4f, b4, vox2);

    k_gemm_relu<256, 256, false, false><<<(NVOX + 63) / 64, 256, 0, stream>>>(
        (const void*)vox2, wv2f, bv2, (void*)out, NVOX);
}

// Round 3
// 677.589 us; speedup vs baseline: 3.2883x; 1.4501x over previous
//
#include <hip/hip_runtime.h>

#define NPTS 500000
#define NVOX 50000

typedef unsigned short u16;
typedef unsigned int u32;
typedef __attribute__((ext_vector_type(8))) short short8;
typedef __attribute__((ext_vector_type(4))) float floatx4;
typedef __attribute__((ext_vector_type(4))) unsigned int uintx4;

__device__ __forceinline__ u16 f2bf(float f) {
    u32 u = __float_as_uint(f);
    u = u + 0x7fffu + ((u >> 16) & 1u);   // RNE
    return (u16)(u >> 16);
}

// ---- K0: swizzle fp32 weight (K x N, row-major) into B-fragment-contiguous bf16 ----
// B-frag for mfma_f32_16x16x32_bf16: lane l holds B[kk*32 + q*8 + j][n], q=l>>4, n=base+(l&15).
// Layout: Wf[((kk*4+q)*N + n)*8 + j]  -> each lane reads 16B contiguous.
__global__ void k_wtransform(const float* __restrict__ W, u16* __restrict__ Wf, int K, int N) {
    int t = blockIdx.x * 256 + threadIdx.x;
    if (t >= K * N) return;
    int k = t / N, n = t - k * N;
    int kk = k >> 5, q = (k >> 3) & 3, j = k & 7;
    Wf[((size_t)((kk * 4 + q) * N + n) << 3) + j] = f2bf(W[t]);
}

// block-diag [[w2x,0],[0,w2r]] (128x64), swizzled
__global__ void k_wcat(const float* __restrict__ w2x, const float* __restrict__ w2r, u16* __restrict__ wcatf) {
    int t = blockIdx.x * 256 + threadIdx.x;
    if (t >= 128 * 64) return;
    int k = t >> 6, n = t & 63;
    float v;
    if (k < 64) v = (n < 32) ? w2x[k * 32 + n] : 0.f;
    else        v = (n >= 32) ? w2r[(k - 64) * 32 + (n - 32)] : 0.f;
    int kk = k >> 5, q = (k >> 3) & 3, j = k & 7;
    wcatf[((size_t)((kk * 4 + q) * 64 + n) << 3) + j] = f2bf(v);
}

// [wax | war] (64x64), swizzled
__global__ void k_watt(const float* __restrict__ wax, const float* __restrict__ war, u16* __restrict__ wattf) {
    int t = blockIdx.x * 256 + threadIdx.x;
    if (t >= 64 * 64) return;
    int k = t >> 6, n = t & 63;
    float v = (n < 32) ? wax[k * 32 + n] : war[k * 32 + (n - 32)];
    int kk = k >> 5, q = (k >> 3) & 3, j = k & 7;
    wattf[((size_t)((kk * 4 + q) * 64 + n) << 3) + j] = f2bf(v);
}

// ---- CSR build: histogram -> scan -> scatter (rank + sorted vid) ----
__global__ void k_hist(const int* __restrict__ idx, int* __restrict__ hcnt) {
    int i = blockIdx.x * 256 + threadIdx.x;
    if (i < NPTS) atomicAdd(&hcnt[idx[i]], 1);
}

__global__ __launch_bounds__(256) void k_scan(const int* __restrict__ hcnt,
                                              int* __restrict__ start, int* __restrict__ cur) {
    __shared__ int wsum[4];
    int t = threadIdx.x;
    int lane = t & 63, w = t >> 6;
    int running = 0;
    for (int base = 0; base < NVOX; base += 256) {
        int c = (base + t < NVOX) ? hcnt[base + t] : 0;
        int v = c;
        #pragma unroll
        for (int d = 1; d < 64; d <<= 1) {
            int o = __shfl_up(v, d, 64);
            if (lane >= d) v += o;
        }
        if (lane == 63) wsum[w] = v;
        __syncthreads();
        int wo = 0;
        #pragma unroll
        for (int k = 0; k < 4; k++) if (k < w) wo += wsum[k];
        int excl = running + wo + v - c;
        if (base + t < NVOX) { start[base + t] = excl; cur[base + t] = excl; }
        running += wsum[0] + wsum[1] + wsum[2] + wsum[3];
        __syncthreads();
    }
}

__global__ void k_scatter(const int* __restrict__ idx, int* __restrict__ cur,
                          int* __restrict__ rank, int* __restrict__ svid) {
    int i = blockIdx.x * 256 + threadIdx.x;
    if (i < NPTS) {
        int v = idx[i];
        int pos = atomicAdd(&cur[v], 1);
        rank[i] = pos;
        svid[pos] = v;
    }
}

// ---- K1: MFMA point feature encoder: 64 points/block, scatter-writes pf2s row rank[i] ----
__global__ __launch_bounds__(256) void k_pointfeat(
    const float* __restrict__ inp, const int* __restrict__ rank,
    const float* __restrict__ w1x, const float* __restrict__ b1x,
    const float* __restrict__ w1r, const float* __restrict__ b1r,
    const u16* __restrict__ wcatf, const float* __restrict__ b2x, const float* __restrict__ b2r,
    const u16* __restrict__ wattf, const float* __restrict__ bax, const float* __restrict__ bar,
    u16* __restrict__ pf2s)
{
    __shared__ u16 hbuf[64 * 136];   // h tile (64x128 +8 pad); reused for pf2 out-tile
    __shared__ u16 cbuf[64 * 72];    // comb tile (64x64 +8 pad)
    __shared__ float wl[512];        // w1x(192) b1x(64) w1r(192) b1r(64)
    __shared__ int lrank[64];
    int t = threadIdx.x;
    int i0 = blockIdx.x * 64;
    for (int s = t; s < 512; s += 256) {
        float v;
        if (s < 192)      v = w1x[s];
        else if (s < 256) v = b1x[s - 192];
        else if (s < 448) v = w1r[s - 256];
        else              v = b1r[s - 448];
        wl[s] = v;
    }
    if (t < 64) lrank[t] = (i0 + t < NPTS) ? rank[i0 + t] : 0;
    __syncthreads();
    {   // layer 1: K=3 on VALU, 4 threads/point each produce 16 h_x + 16 h_r cols
        int m = t >> 2, c = t & 3;
        int i = i0 + m;
        float x0 = 0, x1 = 0, x2 = 0, r0 = 0, r1 = 0, r2 = 0;
        if (i < NPTS) {
            const float* p = inp + (size_t)i * 6;
            x0 = p[0]; x1 = p[1]; x2 = p[2]; r0 = p[3]; r1 = p[4]; r2 = p[5];
        }
        u16* hb = &hbuf[m * 136 + c * 16];
        #pragma unroll
        for (int jp = 0; jp < 8; jp++) {
            int c0 = c * 16 + 2 * jp, c1 = c0 + 1;
            float hx0 = fmaxf(wl[192 + c0] + x0 * wl[c0] + x1 * wl[64 + c0] + x2 * wl[128 + c0], 0.f);
            float hx1 = fmaxf(wl[192 + c1] + x0 * wl[c1] + x1 * wl[64 + c1] + x2 * wl[128 + c1], 0.f);
            float hr0 = fmaxf(wl[448 + c0] + r0 * wl[256 + c0] + r1 * wl[320 + c0] + r2 * wl[384 + c0], 0.f);
            float hr1 = fmaxf(wl[448 + c1] + r0 * wl[256 + c1] + r1 * wl[320 + c1] + r2 * wl[384 + c1], 0.f);
            *(u32*)(hb + 2 * jp)      = (u32)f2bf(hx0) | ((u32)f2bf(hx1) << 16);
            *(u32*)(hb + 64 + 2 * jp) = (u32)f2bf(hr0) | ((u32)f2bf(hr1) << 16);
        }
    }
    __syncthreads();
    int wave = t >> 6, l = t & 63, q = l >> 4, lm = l & 15;
    int n = wave * 16 + lm;    // each wave owns 16 output cols
    // GEMM1: comb(64x64) = h(64x128) @ wcat(128x64)
    floatx4 acc[4];
    #pragma unroll
    for (int a = 0; a < 4; a++) acc[a] = (floatx4){0.f, 0.f, 0.f, 0.f};
    #pragma unroll
    for (int kk = 0; kk < 4; kk++) {
        short8 bfrag = *(const short8*)&wcatf[(size_t)((kk * 4 + q) * 64 + n) << 3];
        #pragma unroll
        for (int tm = 0; tm < 4; tm++) {
            short8 afrag = *(const short8*)&hbuf[(tm * 16 + lm) * 136 + kk * 32 + q * 8];
            acc[tm] = __builtin_amdgcn_mfma_f32_16x16x32_bf16(afrag, bfrag, acc[tm], 0, 0, 0);
        }
    }
    float bv = (n < 32) ? b2x[n] : b2r[n - 32];
    float comb_keep[4][4];
    #pragma unroll
    for (int tm = 0; tm < 4; tm++)
        #pragma unroll
        for (int r = 0; r < 4; r++) {
            float v = fmaxf(acc[tm][r] + bv, 0.f);
            comb_keep[tm][r] = v;
            int m = tm * 16 + q * 4 + r;     // C/D: row = quad*4+reg, col = lane&15
            cbuf[m * 72 + n] = f2bf(v);
        }
    __syncthreads();
    // GEMM2: att(64x64) = comb @ watt; same C-layout as comb -> register-local gating
    floatx4 acc2[4];
    #pragma unroll
    for (int a = 0; a < 4; a++) acc2[a] = (floatx4){0.f, 0.f, 0.f, 0.f};
    #pragma unroll
    for (int kk = 0; kk < 2; kk++) {
        short8 bfrag = *(const short8*)&wattf[(size_t)((kk * 4 + q) * 64 + n) << 3];
        #pragma unroll
        for (int tm = 0; tm < 4; tm++) {
            short8 afrag = *(const short8*)&cbuf[(tm * 16 + lm) * 72 + kk * 32 + q * 8];
            acc2[tm] = __builtin_amdgcn_mfma_f32_16x16x32_bf16(afrag, bfrag, acc2[tm], 0, 0, 0);
        }
    }
    float bv2 = (n < 32) ? bax[n] : bar[n - 32];
    int pp = (n < 32) ? n : 32 + n;   // pf2 col of plain value; gated at pp+32
    #pragma unroll
    for (int tm = 0; tm < 4; tm++)
        #pragma unroll
        for (int r = 0; r < 4; r++) {
            float att = acc2[tm][r] + bv2;
            float sg = 1.f / (1.f + __expf(-att));
            float plain = comb_keep[tm][r];
            float gated = plain * sg;
            int m = tm * 16 + q * 4 + r;
            hbuf[m * 136 + pp] = f2bf(plain);
            hbuf[m * 136 + pp + 32] = f2bf(gated);
        }
    __syncthreads();
    {   // scatter pf2s store to sorted row: 4 threads/row x 64B
        int row = t >> 2, seg = t & 3;
        if (i0 + row < NPTS) {
            const u16* src = &hbuf[row * 136 + seg * 32];
            u16* dst = pf2s + (size_t)lrank[row] * 128 + seg * 32;
            *(uintx4*)dst = *(const uintx4*)src;
            *(uintx4*)(dst + 8) = *(const uintx4*)(src + 8);
        }
    }
}

// ---- segment-max over contiguous sorted pf2s rows (bf16 bit-compare: all values >= 0) ----
__global__ __launch_bounds__(256) void k_segmax(
    const u16* __restrict__ pf2s, const int* __restrict__ start, const int* __restrict__ hcnt,
    u16* __restrict__ voxmax)
{
    int w = threadIdx.x >> 6, l = threadIdx.x & 63;
    int v = blockIdx.x * 4 + w;
    if (v >= NVOX) return;
    int s = start[v], c = hcnt[v];
    const u32* base = (const u32*)pf2s + (size_t)s * 64 + l;
    u32 mlo = 0, mhi = 0;
    for (int e = 0; e < c; e++) {
        u32 u = base[(size_t)e * 64];
        u32 lo = u & 0xffffu, hi = u >> 16;
        mlo = lo > mlo ? lo : mlo;
        mhi = hi > mhi ? hi : mhi;
    }
    ((u32*)voxmax)[(size_t)v * 64 + l] = mlo | (mhi << 16);
}

// ---- generic MFMA GEMM: out = relu(A @ W + bias); A fp32 or bf16; W pre-swizzled bf16 ----
template<int K, int N, bool ABF16, bool OUT_BF16>
__global__ __launch_bounds__(256) void k_gemm_relu(
    const void* __restrict__ Ap, const u16* __restrict__ Wf,
    const float* __restrict__ bias, void* __restrict__ outp, int M)
{
    constexpr int STRIDE = K + 8;
    constexpr int TN = N / 64;
    constexpr int KSTEPS = K / 32;
    constexpr int CW = K / 4;
    __shared__ u16 lds[64 * STRIDE];
    int i0 = blockIdx.x * 64;
    int mcnt = M - i0; if (mcnt > 64) mcnt = 64;
    int t = threadIdx.x;
    {
        int row = t >> 2, cseg = t & 3;
        u16* dst = &lds[row * STRIDE + cseg * CW];
        if (row < mcnt) {
            if (ABF16) {
                const u16* src = (const u16*)Ap + (size_t)(i0 + row) * K + cseg * CW;
                #pragma unroll
                for (int c = 0; c < CW / 8; c++)
                    *(uintx4*)(dst + c * 8) = *(const uintx4*)(src + c * 8);
            } else {
                const float* src = (const float*)Ap + (size_t)(i0 + row) * K + cseg * CW;
                #pragma unroll
                for (int c = 0; c < CW / 8; c++) {
                    float4 v0 = *(const float4*)(src + c * 8);
                    float4 v1 = *(const float4*)(src + c * 8 + 4);
                    short8 rr;
                    rr[0] = f2bf(v0.x); rr[1] = f2bf(v0.y); rr[2] = f2bf(v0.z); rr[3] = f2bf(v0.w);
                    rr[4] = f2bf(v1.x); rr[5] = f2bf(v1.y); rr[6] = f2bf(v1.z); rr[7] = f2bf(v1.w);
                    *(short8*)(dst + c * 8) = rr;
                }
            }
        } else {
            short8 z = {0, 0, 0, 0, 0, 0, 0, 0};
            #pragma unroll
            for (int c = 0; c < CW / 8; c++) *(short8*)(dst + c * 8) = z;
        }
    }
    __syncthreads();
    int wave = t >> 6, l = t & 63;
    int q = l >> 4, lm = l & 15;
    int wn0 = wave * (N / 4);
    floatx4 acc[4][TN];
    #pragma unroll
    for (int a = 0; a < 4; a++)
        #pragma unroll
        for (int b = 0; b < TN; b++) acc[a][b] = (floatx4){0.f, 0.f, 0.f, 0.f};
    #pragma unroll
    for (int kk = 0; kk < KSTEPS; kk++) {
        short8 afrag[4], bfrag[TN];
        #pragma unroll
        for (int tm = 0; tm < 4; tm++)
            afrag[tm] = *(const short8*)&lds[(tm * 16 + lm) * STRIDE + kk * 32 + q * 8];
        #pragma unroll
        for (int tn = 0; tn < TN; tn++)
            bfrag[tn] = *(const short8*)&Wf[(size_t)((kk * 4 + q) * N + wn0 + tn * 16 + lm) * 8];
        #pragma unroll
        for (int tm = 0; tm < 4; tm++)
            #pragma unroll
            for (int tn = 0; tn < TN; tn++)
                acc[tm][tn] = __builtin_amdgcn_mfma_f32_16x16x32_bf16(afrag[tm], bfrag[tn], acc[tm][tn], 0, 0, 0);
    }
    #pragma unroll
    for (int tm = 0; tm < 4; tm++)
        #pragma unroll
        for (int tn = 0; tn < TN; tn++) {
            int n = wn0 + tn * 16 + lm;
            float bv = bias[n];
            #pragma unroll
            for (int r = 0; r < 4; r++) {
                int m = tm * 16 + q * 4 + r;
                if (m < mcnt) {
                    float v = fmaxf(acc[tm][tn][r] + bv, 0.f);
                    if (OUT_BF16) ((u16*)outp)[(size_t)(i0 + m) * N + n] = f2bf(v);
                    else          ((float*)outp)[(size_t)(i0 + m) * N + n] = v;
                }
            }
        }
}

// ---- K3: sorted-order fused point MLP + in-LDS segmented max -> vox2 (few atomics) ----
// 128 sorted rows/block, 8 waves. pf5 never touches global memory.
__global__ __launch_bounds__(512) void k_pointmlp(
    const u16* __restrict__ voxf, const u16* __restrict__ pf2s, const int* __restrict__ svid,
    const u16* __restrict__ w3f, const float* __restrict__ b3,
    const u16* __restrict__ w4f, const float* __restrict__ b4,
    float* __restrict__ vox2)
{
    constexpr int STRIDE = 264;
    __shared__ u16 lds[128 * STRIDE];
    __shared__ int lvid[128];
    int i0 = blockIdx.x * 128;
    int mcnt = NPTS - i0; if (mcnt > 128) mcnt = 128;
    int t = threadIdx.x;
    if (t < 128) lvid[t] = (t < mcnt) ? svid[i0 + t] : -1;
    {
        int row = t >> 2, cseg = t & 3;       // 4 threads/row, 64 bf16 each
        u16* dst = &lds[row * STRIDE + cseg * 64];
        if (row < mcnt) {
            const u16* src;
            if (cseg < 2) src = voxf + (size_t)svid[i0 + row] * 128 + cseg * 64;     // pg half (sorted: high locality)
            else          src = pf2s + (size_t)(i0 + row) * 128 + (cseg - 2) * 64;   // pf2 half (coalesced)
            #pragma unroll
            for (int c = 0; c < 8; c++)
                *(uintx4*)(dst + c * 8) = *(const uintx4*)(src + c * 8);
        } else {
            uintx4 z = {0, 0, 0, 0};
            #pragma unroll
            for (int c = 0; c < 8; c++) *(uintx4*)(dst + c * 8) = z;
        }
    }
    __syncthreads();
    int wave = t >> 6, l = t & 63;
    int q = l >> 4, lm = l & 15;
    int rw = (wave >> 2) * 64;     // row offset of this wave's 64x64 C tile
    int wn0 = (wave & 3) * 64;     // col offset
    floatx4 acc[4][4];
    #pragma unroll
    for (int a = 0; a < 4; a++)
        #pragma unroll
        for (int b = 0; b < 4; b++) acc[a][b] = (floatx4){0.f, 0.f, 0.f, 0.f};
    #pragma unroll
    for (int kk = 0; kk < 8; kk++) {
        short8 afrag[4], bfrag[4];
        #pragma unroll
        for (int tm = 0; tm < 4; tm++)
            afrag[tm] = *(const short8*)&lds[(rw + tm * 16 + lm) * STRIDE + kk * 32 + q * 8];
        #pragma unroll
        for (int tn = 0; tn < 4; tn++)
            bfrag[tn] = *(const short8*)&w3f[(size_t)((kk * 4 + q) * 256 + wn0 + tn * 16 + lm) * 8];
        #pragma unroll
        for (int tm = 0; tm < 4; tm++)
            #pragma unroll
            for (int tn = 0; tn < 4; tn++)
                acc[tm][tn] = __builtin_amdgcn_mfma_f32_16x16x32_bf16(afrag[tm], bfrag[tn], acc[tm][tn], 0, 0, 0);
    }
    __syncthreads();
    // H = relu(acc + b3) -> LDS bf16
    #pragma unroll
    for (int tm = 0; tm < 4; tm++)
        #pragma unroll
        for (int tn = 0; tn < 4; tn++) {
            int n = wn0 + tn * 16 + lm;
            float bv = b3[n];
            #pragma unroll
            for (int r = 0; r < 4; r++) {
                int m = rw + tm * 16 + q * 4 + r;
                lds[m * STRIDE + n] = f2bf(fmaxf(acc[tm][tn][r] + bv, 0.f));
            }
        }
    __syncthreads();
    floatx4 acc2[4][4];
    #pragma unroll
    for (int a = 0; a < 4; a++)
        #pragma unroll
        for (int b = 0; b < 4; b++) acc2[a][b] = (floatx4){0.f, 0.f, 0.f, 0.f};
    #pragma unroll
    for (int kk = 0; kk < 8; kk++) {
        short8 afrag[4], bfrag[4];
        #pragma unroll
        for (int tm = 0; tm < 4; tm++)
            afrag[tm] = *(const short8*)&lds[(rw + tm * 16 + lm) * STRIDE + kk * 32 + q * 8];
        #pragma unroll
        for (int tn = 0; tn < 4; tn++)
            bfrag[tn] = *(const short8*)&w4f[(size_t)((kk * 4 + q) * 256 + wn0 + tn * 16 + lm) * 8];
        #pragma unroll
        for (int tm = 0; tm < 4; tm++)
            #pragma unroll
            for (int tn = 0; tn < 4; tn++)
                acc2[tm][tn] = __builtin_amdgcn_mfma_f32_16x16x32_bf16(afrag[tm], bfrag[tn], acc2[tm][tn], 0, 0, 0);
    }
    __syncthreads();   // all waves done reading H before overwrite
    // pf5 = relu(acc2 + b4) -> LDS bf16 (overwrite)
    #pragma unroll
    for (int tm = 0; tm < 4; tm++)
        #pragma unroll
        for (int tn = 0; tn < 4; tn++) {
            int n = wn0 + tn * 16 + lm;
            float bv = b4[n];
            #pragma unroll
            for (int r = 0; r < 4; r++) {
                int m = rw + tm * 16 + q * 4 + r;
                lds[m * STRIDE + n] = f2bf(fmaxf(acc2[tm][tn][r] + bv, 0.f));
            }
        }
    __syncthreads();
    // segmented max over sorted vid runs: thread owns u32 col-pair x 32 rows
    {
        int c2 = t & 127;          // u32 column (cols 2c2, 2c2+1)
        int h = t >> 7;            // row quarter
        int r0 = h * 32;
        int r1 = r0 + 32; if (r1 > mcnt) r1 = mcnt;
        u32 mlo = 0, mhi = 0;
        int pvid = -1;
        for (int r = r0; r < r1; r++) {
            int vid = lvid[r];
            if (vid != pvid) {
                if (pvid >= 0) {
                    int* addr = (int*)(vox2 + (size_t)pvid * 256 + 2 * c2);
                    if (mlo) atomicMax(addr, (int)(mlo << 16));
                    if (mhi) atomicMax(addr + 1, (int)(mhi << 16));
                }
                pvid = vid; mlo = 0; mhi = 0;
            }
            u32 u = *(const u32*)&lds[r * STRIDE + 2 * c2];
            u32 lo = u & 0xffffu, hi = u >> 16;
            mlo = lo > mlo ? lo : mlo;
            mhi = hi > mhi ? hi : mhi;
        }
        if (pvid >= 0) {
            int* addr = (int*)(vox2 + (size_t)pvid * 256 + 2 * c2);
            if (mlo) atomicMax(addr, (int)(mlo << 16));
            if (mhi) atomicMax(addr + 1, (int)(mhi << 16));
        }
    }
}

extern "C" void kernel_launch(void* const* d_in, const int* in_sizes, int n_in,
                              void* d_out, int out_size, void* d_ws, size_t ws_size,
                              hipStream_t stream) {
    const float* inp = (const float*)d_in[0];
    const int*   idx = (const int*)d_in[1];
    const float* w1x = (const float*)d_in[3];  const float* b1x = (const float*)d_in[4];
    const float* w2x = (const float*)d_in[5];  const float* b2x = (const float*)d_in[6];
    const float* w1r = (const float*)d_in[7];  const float* b1r = (const float*)d_in[8];
    const float* w2r = (const float*)d_in[9];  const float* b2r = (const float*)d_in[10];
    const float* wax = (const float*)d_in[11]; const float* bax = (const float*)d_in[12];
    const float* war = (const float*)d_in[13]; const float* bar = (const float*)d_in[14];
    const float* wv1 = (const float*)d_in[15]; const float* bv1 = (const float*)d_in[16];
    const float* w3  = (const float*)d_in[17]; const float* b3  = (const float*)d_in[18];
    const float* w4  = (const float*)d_in[19]; const float* b4  = (const float*)d_in[20];
    const float* wv2 = (const float*)d_in[21]; const float* bv2 = (const float*)d_in[22];
    float* out = (float*)d_out;

    char* ws = (char*)d_ws;
    u16*   pf2s   = (u16*)ws;   ws += (size_t)NPTS * 128 * sizeof(u16);   // 128 MB (sorted rows)
    u16*   voxmax = (u16*)ws;   ws += (size_t)NVOX * 128 * sizeof(u16);   // 12.8 MB
    u16*   voxf   = (u16*)ws;   ws += (size_t)NVOX * 128 * sizeof(u16);   // 12.8 MB
    float* vox2   = (float*)ws; ws += (size_t)NVOX * 256 * sizeof(float); // 51.2 MB
    u16*   w3f    = (u16*)ws;   ws += 65536 * sizeof(u16);
    u16*   w4f    = (u16*)ws;   ws += 65536 * sizeof(u16);
    u16*   wv1f   = (u16*)ws;   ws += 16384 * sizeof(u16);
    u16*   wv2f   = (u16*)ws;   ws += 65536 * sizeof(u16);
    u16*   wcatf  = (u16*)ws;   ws += 8192 * sizeof(u16);
    u16*   wattf  = (u16*)ws;   ws += 4096 * sizeof(u16);
    int*   hcnt   = (int*)ws;   ws += (size_t)NVOX * sizeof(int);
    int*   start  = (int*)ws;   ws += (size_t)NVOX * sizeof(int);
    int*   cur    = (int*)ws;   ws += (size_t)NVOX * sizeof(int);
    int*   rank   = (int*)ws;   ws += (size_t)NPTS * sizeof(int);
    int*   svid   = (int*)ws;   ws += (size_t)NPTS * sizeof(int);

    hipMemsetAsync(hcnt, 0, (size_t)NVOX * sizeof(int), stream);
    hipMemsetAsync(vox2, 0, (size_t)NVOX * 256 * sizeof(float), stream);

    k_wtransform<<<256, 256, 0, stream>>>(w3, w3f, 256, 256);
    k_wtransform<<<256, 256, 0, stream>>>(w4, w4f, 256, 256);
    k_wtransform<<<64,  256, 0, stream>>>(wv1, wv1f, 128, 128);
    k_wtransform<<<256, 256, 0, stream>>>(wv2, wv2f, 256, 256);
    k_wcat<<<32, 256, 0, stream>>>(w2x, w2r, wcatf);
    k_watt<<<16, 256, 0, stream>>>(wax, war, wattf);

    k_hist<<<(NPTS + 255) / 256, 256, 0, stream>>>(idx, hcnt);
    k_scan<<<1, 256, 0, stream>>>(hcnt, start, cur);
    k_scatter<<<(NPTS + 255) / 256, 256, 0, stream>>>(idx, cur, rank, svid);

    k_pointfeat<<<(NPTS + 63) / 64, 256, 0, stream>>>(
        inp, rank, w1x, b1x, w1r, b1r, wcatf, b2x, b2r, wattf, bax, bar, pf2s);

    k_segmax<<<(NVOX + 3) / 4, 256, 0, stream>>>(pf2s, start, hcnt, voxmax);

    k_gemm_relu<128, 128, true, true><<<(NVOX + 63) / 64, 256, 0, stream>>>(
        (const void*)voxmax, wv1f, bv1, (void*)voxf, NVOX);

    k_pointmlp<<<(NPTS + 127) / 128, 512, 0, stream>>>(
        voxf, pf2s, svid, w3f, b3, w4f, b4, vox2);

    k_gemm_relu<256, 256, false, false><<<(NVOX + 63) / 64, 256, 0, stream>>>(
        (const void*)vox2, wv2f, bv2, (void*)out, NVOX);
}

// Round 4
// 524.065 us; speedup vs baseline: 4.2516x; 1.2929x over previous
//
#include <hip/hip_runtime.h>

#define NPTS 500000
#define NVOX 50000
#define NBLK 196   // ceil(NVOX/256)

typedef unsigned short u16;
typedef unsigned int u32;
typedef __attribute__((ext_vector_type(8))) short short8;
typedef __attribute__((ext_vector_type(4))) float floatx4;
typedef __attribute__((ext_vector_type(4))) unsigned int uintx4;

__device__ __forceinline__ u16 f2bf(float f) {
    u32 u = __float_as_uint(f);
    u = u + 0x7fffu + ((u >> 16) & 1u);   // RNE
    return (u16)(u >> 16);
}

// ---- K0: swizzle fp32 weight (K x N, row-major) into B-fragment-contiguous bf16 ----
// B-frag for mfma_f32_16x16x32_bf16: lane l holds B[kk*32 + q*8 + j][n], q=l>>4, n=base+(l&15).
// Layout: Wf[((kk*4+q)*N + n)*8 + j]  -> each lane reads 16B contiguous.
__global__ void k_wtransform(const float* __restrict__ W, u16* __restrict__ Wf, int K, int N) {
    int t = blockIdx.x * 256 + threadIdx.x;
    if (t >= K * N) return;
    int k = t / N, n = t - k * N;
    int kk = k >> 5, q = (k >> 3) & 3, j = k & 7;
    Wf[((size_t)((kk * 4 + q) * N + n) << 3) + j] = f2bf(W[t]);
}

// block-diag [[w2x,0],[0,w2r]] (128x64), swizzled
__global__ void k_wcat(const float* __restrict__ w2x, const float* __restrict__ w2r, u16* __restrict__ wcatf) {
    int t = blockIdx.x * 256 + threadIdx.x;
    if (t >= 128 * 64) return;
    int k = t >> 6, n = t & 63;
    float v;
    if (k < 64) v = (n < 32) ? w2x[k * 32 + n] : 0.f;
    else        v = (n >= 32) ? w2r[(k - 64) * 32 + (n - 32)] : 0.f;
    int kk = k >> 5, q = (k >> 3) & 3, j = k & 7;
    wcatf[((size_t)((kk * 4 + q) * 64 + n) << 3) + j] = f2bf(v);
}

// [wax | war] (64x64), swizzled
__global__ void k_watt(const float* __restrict__ wax, const float* __restrict__ war, u16* __restrict__ wattf) {
    int t = blockIdx.x * 256 + threadIdx.x;
    if (t >= 64 * 64) return;
    int k = t >> 6, n = t & 63;
    float v = (n < 32) ? wax[k * 32 + n] : war[k * 32 + (n - 32)];
    int kk = k >> 5, q = (k >> 3) & 3, j = k & 7;
    wattf[((size_t)((kk * 4 + q) * 64 + n) << 3) + j] = f2bf(v);
}

// ---- CSR build: histogram -> 3-phase parallel scan -> scatter (rank + sorted vid) ----
__global__ void k_hist(const int* __restrict__ idx, int* __restrict__ hcnt) {
    int i = blockIdx.x * 256 + threadIdx.x;
    if (i < NPTS) atomicAdd(&hcnt[idx[i]], 1);
}

// phase A: per-block sums of 256 counts
__global__ __launch_bounds__(256) void k_scan1(const int* __restrict__ hcnt, int* __restrict__ bsum) {
    __shared__ int wsum[4];
    int t = threadIdx.x;
    int i = blockIdx.x * 256 + t;
    int c = (i < NVOX) ? hcnt[i] : 0;
    #pragma unroll
    for (int d = 32; d >= 1; d >>= 1) c += __shfl_xor(c, d, 64);
    if ((t & 63) == 0) wsum[t >> 6] = c;
    __syncthreads();
    if (t == 0) bsum[blockIdx.x] = wsum[0] + wsum[1] + wsum[2] + wsum[3];
}

// phase B: exclusive scan of NBLK block sums (single tiny block)
__global__ __launch_bounds__(256) void k_scan2(const int* __restrict__ bsum, int* __restrict__ boff) {
    __shared__ int wsum[4];
    int t = threadIdx.x, lane = t & 63, w = t >> 6;
    int c = (t < NBLK) ? bsum[t] : 0;
    int v = c;
    #pragma unroll
    for (int d = 1; d < 64; d <<= 1) {
        int o = __shfl_up(v, d, 64);
        if (lane >= d) v += o;
    }
    if (lane == 63) wsum[w] = v;
    __syncthreads();
    int wo = 0;
    #pragma unroll
    for (int k = 0; k < 4; k++) if (k < w) wo += wsum[k];
    if (t < NBLK) boff[t] = wo + v - c;
}

// phase C: per-block exclusive scan + block offset -> start, cur
__global__ __launch_bounds__(256) void k_scan3(const int* __restrict__ hcnt, const int* __restrict__ boff,
                                               int* __restrict__ start, int* __restrict__ cur) {
    __shared__ int wsum[4];
    int t = threadIdx.x, lane = t & 63, w = t >> 6;
    int i = blockIdx.x * 256 + t;
    int c = (i < NVOX) ? hcnt[i] : 0;
    int v = c;
    #pragma unroll
    for (int d = 1; d < 64; d <<= 1) {
        int o = __shfl_up(v, d, 64);
        if (lane >= d) v += o;
    }
    if (lane == 63) wsum[w] = v;
    __syncthreads();
    int wo = 0;
    #pragma unroll
    for (int k = 0; k < 4; k++) if (k < w) wo += wsum[k];
    if (i < NVOX) {
        int excl = boff[blockIdx.x] + wo + v - c;
        start[i] = excl;
        cur[i] = excl;
    }
}

__global__ void k_scatter(const int* __restrict__ idx, int* __restrict__ cur,
                          int* __restrict__ rank, int* __restrict__ svid) {
    int i = blockIdx.x * 256 + threadIdx.x;
    if (i < NPTS) {
        int v = idx[i];
        int pos = atomicAdd(&cur[v], 1);
        rank[i] = pos;
        svid[pos] = v;
    }
}

// ---- K1: MFMA point feature encoder: 64 points/block, scatter-writes pf2s row rank[i] ----
__global__ __launch_bounds__(256) void k_pointfeat(
    const float* __restrict__ inp, const int* __restrict__ rank,
    const float* __restrict__ w1x, const float* __restrict__ b1x,
    const float* __restrict__ w1r, const float* __restrict__ b1r,
    const u16* __restrict__ wcatf, const float* __restrict__ b2x, const float* __restrict__ b2r,
    const u16* __restrict__ wattf, const float* __restrict__ bax, const float* __restrict__ bar,
    u16* __restrict__ pf2s)
{
    __shared__ u16 hbuf[64 * 136];   // h tile (64x128 +8 pad); reused for pf2 out-tile
    __shared__ u16 cbuf[64 * 72];    // comb tile (64x64 +8 pad)
    __shared__ float wl[512];        // w1x(192) b1x(64) w1r(192) b1r(64)
    __shared__ int lrank[64];
    int t = threadIdx.x;
    int i0 = blockIdx.x * 64;
    for (int s = t; s < 512; s += 256) {
        float v;
        if (s < 192)      v = w1x[s];
        else if (s < 256) v = b1x[s - 192];
        else if (s < 448) v = w1r[s - 256];
        else              v = b1r[s - 448];
        wl[s] = v;
    }
    if (t < 64) lrank[t] = (i0 + t < NPTS) ? rank[i0 + t] : 0;
    __syncthreads();
    {   // layer 1: K=3 on VALU, 4 threads/point each produce 16 h_x + 16 h_r cols
        int m = t >> 2, c = t & 3;
        int i = i0 + m;
        float x0 = 0, x1 = 0, x2 = 0, r0 = 0, r1 = 0, r2 = 0;
        if (i < NPTS) {
            const float* p = inp + (size_t)i * 6;
            x0 = p[0]; x1 = p[1]; x2 = p[2]; r0 = p[3]; r1 = p[4]; r2 = p[5];
        }
        u16* hb = &hbuf[m * 136 + c * 16];
        #pragma unroll
        for (int jp = 0; jp < 8; jp++) {
            int c0 = c * 16 + 2 * jp, c1 = c0 + 1;
            float hx0 = fmaxf(wl[192 + c0] + x0 * wl[c0] + x1 * wl[64 + c0] + x2 * wl[128 + c0], 0.f);
            float hx1 = fmaxf(wl[192 + c1] + x0 * wl[c1] + x1 * wl[64 + c1] + x2 * wl[128 + c1], 0.f);
            float hr0 = fmaxf(wl[448 + c0] + r0 * wl[256 + c0] + r1 * wl[320 + c0] + r2 * wl[384 + c0], 0.f);
            float hr1 = fmaxf(wl[448 + c1] + r0 * wl[256 + c1] + r1 * wl[320 + c1] + r2 * wl[384 + c1], 0.f);
            *(u32*)(hb + 2 * jp)      = (u32)f2bf(hx0) | ((u32)f2bf(hx1) << 16);
            *(u32*)(hb + 64 + 2 * jp) = (u32)f2bf(hr0) | ((u32)f2bf(hr1) << 16);
        }
    }
    __syncthreads();
    int wave = t >> 6, l = t & 63, q = l >> 4, lm = l & 15;
    int n = wave * 16 + lm;    // each wave owns 16 output cols
    // GEMM1: comb(64x64) = h(64x128) @ wcat(128x64)
    floatx4 acc[4];
    #pragma unroll
    for (int a = 0; a < 4; a++) acc[a] = (floatx4){0.f, 0.f, 0.f, 0.f};
    #pragma unroll
    for (int kk = 0; kk < 4; kk++) {
        short8 bfrag = *(const short8*)&wcatf[(size_t)((kk * 4 + q) * 64 + n) << 3];
        #pragma unroll
        for (int tm = 0; tm < 4; tm++) {
            short8 afrag = *(const short8*)&hbuf[(tm * 16 + lm) * 136 + kk * 32 + q * 8];
            acc[tm] = __builtin_amdgcn_mfma_f32_16x16x32_bf16(afrag, bfrag, acc[tm], 0, 0, 0);
        }
    }
    float bv = (n < 32) ? b2x[n] : b2r[n - 32];
    float comb_keep[4][4];
    #pragma unroll
    for (int tm = 0; tm < 4; tm++)
        #pragma unroll
        for (int r = 0; r < 4; r++) {
            float v = fmaxf(acc[tm][r] + bv, 0.f);
            comb_keep[tm][r] = v;
            int m = tm * 16 + q * 4 + r;     // C/D: row = quad*4+reg, col = lane&15
            cbuf[m * 72 + n] = f2bf(v);
        }
    __syncthreads();
    // GEMM2: att(64x64) = comb @ watt; same C-layout as comb -> register-local gating
    floatx4 acc2[4];
    #pragma unroll
    for (int a = 0; a < 4; a++) acc2[a] = (floatx4){0.f, 0.f, 0.f, 0.f};
    #pragma unroll
    for (int kk = 0; kk < 2; kk++) {
        short8 bfrag = *(const short8*)&wattf[(size_t)((kk * 4 + q) * 64 + n) << 3];
        #pragma unroll
        for (int tm = 0; tm < 4; tm++) {
            short8 afrag = *(const short8*)&cbuf[(tm * 16 + lm) * 72 + kk * 32 + q * 8];
            acc2[tm] = __builtin_amdgcn_mfma_f32_16x16x32_bf16(afrag, bfrag, acc2[tm], 0, 0, 0);
        }
    }
    float bv2 = (n < 32) ? bax[n] : bar[n - 32];
    int pp = (n < 32) ? n : 32 + n;   // pf2 col of plain value; gated at pp+32
    #pragma unroll
    for (int tm = 0; tm < 4; tm++)
        #pragma unroll
        for (int r = 0; r < 4; r++) {
            float att = acc2[tm][r] + bv2;
            float sg = 1.f / (1.f + __expf(-att));
            float plain = comb_keep[tm][r];
            float gated = plain * sg;
            int m = tm * 16 + q * 4 + r;
            hbuf[m * 136 + pp] = f2bf(plain);
            hbuf[m * 136 + pp + 32] = f2bf(gated);
        }
    __syncthreads();
    {   // scatter pf2s store to sorted row: 4 threads/row x 64B
        int row = t >> 2, seg = t & 3;
        if (i0 + row < NPTS) {
            const u16* src = &hbuf[row * 136 + seg * 32];
            u16* dst = pf2s + (size_t)lrank[row] * 128 + seg * 32;
            *(uintx4*)dst = *(const uintx4*)src;
            *(uintx4*)(dst + 8) = *(const uintx4*)(src + 8);
        }
    }
}

// ---- segment-max over contiguous sorted pf2s rows (bf16 bit-compare: all values >= 0) ----
__global__ __launch_bounds__(256) void k_segmax(
    const u16* __restrict__ pf2s, const int* __restrict__ start, const int* __restrict__ hcnt,
    u16* __restrict__ voxmax)
{
    int w = threadIdx.x >> 6, l = threadIdx.x & 63;
    int v = blockIdx.x * 4 + w;
    if (v >= NVOX) return;
    int s = start[v], c = hcnt[v];
    const u32* base = (const u32*)pf2s + (size_t)s * 64 + l;
    u32 mlo = 0, mhi = 0;
    for (int e = 0; e < c; e++) {
        u32 u = base[(size_t)e * 64];
        u32 lo = u & 0xffffu, hi = u >> 16;
        mlo = lo > mlo ? lo : mlo;
        mhi = hi > mhi ? hi : mhi;
    }
    ((u32*)voxmax)[(size_t)v * 64 + l] = mlo | (mhi << 16);
}

// ---- generic MFMA GEMM: out = relu(A @ W + bias); A fp32 or bf16; W pre-swizzled bf16 ----
template<int K, int N, bool ABF16, bool OUT_BF16>
__global__ __launch_bounds__(256) void k_gemm_relu(
    const void* __restrict__ Ap, const u16* __restrict__ Wf,
    const float* __restrict__ bias, void* __restrict__ outp, int M)
{
    constexpr int STRIDE = K + 8;
    constexpr int TN = N / 64;
    constexpr int KSTEPS = K / 32;
    constexpr int CW = K / 4;
    __shared__ u16 lds[64 * STRIDE];
    int i0 = blockIdx.x * 64;
    int mcnt = M - i0; if (mcnt > 64) mcnt = 64;
    int t = threadIdx.x;
    {
        int row = t >> 2, cseg = t & 3;
        u16* dst = &lds[row * STRIDE + cseg * CW];
        if (row < mcnt) {
            if (ABF16) {
                const u16* src = (const u16*)Ap + (size_t)(i0 + row) * K + cseg * CW;
                #pragma unroll
                for (int c = 0; c < CW / 8; c++)
                    *(uintx4*)(dst + c * 8) = *(const uintx4*)(src + c * 8);
            } else {
                const float* src = (const float*)Ap + (size_t)(i0 + row) * K + cseg * CW;
                #pragma unroll
                for (int c = 0; c < CW / 8; c++) {
                    float4 v0 = *(const float4*)(src + c * 8);
                    float4 v1 = *(const float4*)(src + c * 8 + 4);
                    short8 rr;
                    rr[0] = f2bf(v0.x); rr[1] = f2bf(v0.y); rr[2] = f2bf(v0.z); rr[3] = f2bf(v0.w);
                    rr[4] = f2bf(v1.x); rr[5] = f2bf(v1.y); rr[6] = f2bf(v1.z); rr[7] = f2bf(v1.w);
                    *(short8*)(dst + c * 8) = rr;
                }
            }
        } else {
            short8 z = {0, 0, 0, 0, 0, 0, 0, 0};
            #pragma unroll
            for (int c = 0; c < CW / 8; c++) *(short8*)(dst + c * 8) = z;
        }
    }
    __syncthreads();
    int wave = t >> 6, l = t & 63;
    int q = l >> 4, lm = l & 15;
    int wn0 = wave * (N / 4);
    floatx4 acc[4][TN];
    #pragma unroll
    for (int a = 0; a < 4; a++)
        #pragma unroll
        for (int b = 0; b < TN; b++) acc[a][b] = (floatx4){0.f, 0.f, 0.f, 0.f};
    #pragma unroll
    for (int kk = 0; kk < KSTEPS; kk++) {
        short8 afrag[4], bfrag[TN];
        #pragma unroll
        for (int tm = 0; tm < 4; tm++)
            afrag[tm] = *(const short8*)&lds[(tm * 16 + lm) * STRIDE + kk * 32 + q * 8];
        #pragma unroll
        for (int tn = 0; tn < TN; tn++)
            bfrag[tn] = *(const short8*)&Wf[(size_t)((kk * 4 + q) * N + wn0 + tn * 16 + lm) * 8];
        #pragma unroll
        for (int tm = 0; tm < 4; tm++)
            #pragma unroll
            for (int tn = 0; tn < TN; tn++)
                acc[tm][tn] = __builtin_amdgcn_mfma_f32_16x16x32_bf16(afrag[tm], bfrag[tn], acc[tm][tn], 0, 0, 0);
    }
    #pragma unroll
    for (int tm = 0; tm < 4; tm++)
        #pragma unroll
        for (int tn = 0; tn < TN; tn++) {
            int n = wn0 + tn * 16 + lm;
            float bv = bias[n];
            #pragma unroll
            for (int r = 0; r < 4; r++) {
                int m = tm * 16 + q * 4 + r;
                if (m < mcnt) {
                    float v = fmaxf(acc[tm][tn][r] + bv, 0.f);
                    if (OUT_BF16) ((u16*)outp)[(size_t)(i0 + m) * N + n] = f2bf(v);
                    else          ((float*)outp)[(size_t)(i0 + m) * N + n] = v;
                }
            }
        }
}

// ---- K3: sorted-order fused point MLP + in-LDS segmented max -> vox2 ----
// 64 sorted rows/block, 4 waves, LDS 34 KB -> 4 blocks/CU. pf5 never touches global.
__global__ __launch_bounds__(256) void k_pointmlp(
    const u16* __restrict__ voxf, const u16* __restrict__ pf2s, const int* __restrict__ svid,
    const u16* __restrict__ w3f, const float* __restrict__ b3,
    const u16* __restrict__ w4f, const float* __restrict__ b4,
    float* __restrict__ vox2)
{
    constexpr int STRIDE = 264;
    __shared__ u16 lds[64 * STRIDE];
    __shared__ int lvid[64];
    int i0 = blockIdx.x * 64;
    int mcnt = NPTS - i0; if (mcnt > 64) mcnt = 64;
    int t = threadIdx.x;
    if (t < 64) lvid[t] = (t < mcnt) ? svid[i0 + t] : -1;
    {
        int row = t >> 2, cseg = t & 3;       // 4 threads/row, 64 bf16 each
        u16* dst = &lds[row * STRIDE + cseg * 64];
        if (row < mcnt) {
            const u16* src;
            if (cseg < 2) src = voxf + (size_t)svid[i0 + row] * 128 + cseg * 64;     // pg half (sorted: high locality)
            else          src = pf2s + (size_t)(i0 + row) * 128 + (cseg - 2) * 64;   // pf2 half (coalesced)
            #pragma unroll
            for (int c = 0; c < 8; c++)
                *(uintx4*)(dst + c * 8) = *(const uintx4*)(src + c * 8);
        } else {
            uintx4 z = {0, 0, 0, 0};
            #pragma unroll
            for (int c = 0; c < 8; c++) *(uintx4*)(dst + c * 8) = z;
        }
    }
    __syncthreads();
    int wave = t >> 6, l = t & 63;
    int q = l >> 4, lm = l & 15;
    int wn0 = wave * 64;     // wave's 64-col stripe, rows 0..63
    floatx4 acc[4][4];
    #pragma unroll
    for (int a = 0; a < 4; a++)
        #pragma unroll
        for (int b = 0; b < 4; b++) acc[a][b] = (floatx4){0.f, 0.f, 0.f, 0.f};
    #pragma unroll
    for (int kk = 0; kk < 8; kk++) {
        short8 afrag[4], bfrag[4];
        #pragma unroll
        for (int tm = 0; tm < 4; tm++)
            afrag[tm] = *(const short8*)&lds[(tm * 16 + lm) * STRIDE + kk * 32 + q * 8];
        #pragma unroll
        for (int tn = 0; tn < 4; tn++)
            bfrag[tn] = *(const short8*)&w3f[(size_t)((kk * 4 + q) * 256 + wn0 + tn * 16 + lm) * 8];
        #pragma unroll
        for (int tm = 0; tm < 4; tm++)
            #pragma unroll
            for (int tn = 0; tn < 4; tn++)
                acc[tm][tn] = __builtin_amdgcn_mfma_f32_16x16x32_bf16(afrag[tm], bfrag[tn], acc[tm][tn], 0, 0, 0);
    }
    __syncthreads();
    // H = relu(acc + b3) -> LDS bf16
    #pragma unroll
    for (int tm = 0; tm < 4; tm++)
        #pragma unroll
        for (int tn = 0; tn < 4; tn++) {
            int n = wn0 + tn * 16 + lm;
            float bv = b3[n];
            #pragma unroll
            for (int r = 0; r < 4; r++) {
                int m = tm * 16 + q * 4 + r;
                lds[m * STRIDE + n] = f2bf(fmaxf(acc[tm][tn][r] + bv, 0.f));
            }
        }
    __syncthreads();
    floatx4 acc2[4][4];
    #pragma unroll
    for (int a = 0; a < 4; a++)
        #pragma unroll
        for (int b = 0; b < 4; b++) acc2[a][b] = (floatx4){0.f, 0.f, 0.f, 0.f};
    #pragma unroll
    for (int kk = 0; kk < 8; kk++) {
        short8 afrag[4], bfrag[4];
        #pragma unroll
        for (int tm = 0; tm < 4; tm++)
            afrag[tm] = *(const short8*)&lds[(tm * 16 + lm) * STRIDE + kk * 32 + q * 8];
        #pragma unroll
        for (int tn = 0; tn < 4; tn++)
            bfrag[tn] = *(const short8*)&w4f[(size_t)((kk * 4 + q) * 256 + wn0 + tn * 16 + lm) * 8];
        #pragma unroll
        for (int tm = 0; tm < 4; tm++)
            #pragma unroll
            for (int tn = 0; tn < 4; tn++)
                acc2[tm][tn] = __builtin_amdgcn_mfma_f32_16x16x32_bf16(afrag[tm], bfrag[tn], acc2[tm][tn], 0, 0, 0);
    }
    __syncthreads();   // all waves done reading H before overwrite
    // pf5 = relu(acc2 + b4) -> LDS bf16 (overwrite)
    #pragma unroll
    for (int tm = 0; tm < 4; tm++)
        #pragma unroll
        for (int tn = 0; tn < 4; tn++) {
            int n = wn0 + tn * 16 + lm;
            float bv = b4[n];
            #pragma unroll
            for (int r = 0; r < 4; r++) {
                int m = tm * 16 + q * 4 + r;
                lds[m * STRIDE + n] = f2bf(fmaxf(acc2[tm][tn][r] + bv, 0.f));
            }
        }
    __syncthreads();
    // segmented max over sorted vid runs: thread owns u32 col-pair x 32 rows
    {
        int c2 = t & 127;          // u32 column (cols 2c2, 2c2+1)
        int h = t >> 7;            // row half
        int r0 = h * 32;
        int r1 = r0 + 32; if (r1 > mcnt) r1 = mcnt;
        u32 mlo = 0, mhi = 0;
        int pvid = -1;
        for (int r = r0; r < r1; r++) {
            int vid = lvid[r];
            if (vid != pvid) {
                if (pvid >= 0) {
                    int* addr = (int*)(vox2 + (size_t)pvid * 256 + 2 * c2);
                    if (mlo) atomicMax(addr, (int)(mlo << 16));
                    if (mhi) atomicMax(addr + 1, (int)(mhi << 16));
                }
                pvid = vid; mlo = 0; mhi = 0;
            }
            u32 u = *(const u32*)&lds[r * STRIDE + 2 * c2];
            u32 lo = u & 0xffffu, hi = u >> 16;
            mlo = lo > mlo ? lo : mlo;
            mhi = hi > mhi ? hi : mhi;
        }
        if (pvid >= 0) {
            int* addr = (int*)(vox2 + (size_t)pvid * 256 + 2 * c2);
            if (mlo) atomicMax(addr, (int)(mlo << 16));
            if (mhi) atomicMax(addr + 1, (int)(mhi << 16));
        }
    }
}

extern "C" void kernel_launch(void* const* d_in, const int* in_sizes, int n_in,
                              void* d_out, int out_size, void* d_ws, size_t ws_size,
                              hipStream_t stream) {
    const float* inp = (const float*)d_in[0];
    const int*   idx = (const int*)d_in[1];
    const float* w1x = (const float*)d_in[3];  const float* b1x = (const float*)d_in[4];
    const float* w2x = (const float*)d_in[5];  const float* b2x = (const float*)d_in[6];
    const float* w1r = (const float*)d_in[7];  const float* b1r = (const float*)d_in[8];
    const float* w2r = (const float*)d_in[9];  const float* b2r = (const float*)d_in[10];
    const float* wax = (const float*)d_in[11]; const float* bax = (const float*)d_in[12];
    const float* war = (const float*)d_in[13]; const float* bar = (const float*)d_in[14];
    const float* wv1 = (const float*)d_in[15]; const float* bv1 = (const float*)d_in[16];
    const float* w3  = (const float*)d_in[17]; const float* b3  = (const float*)d_in[18];
    const float* w4  = (const float*)d_in[19]; const float* b4  = (const float*)d_in[20];
    const float* wv2 = (const float*)d_in[21]; const float* bv2 = (const float*)d_in[22];
    float* out = (float*)d_out;

    char* ws = (char*)d_ws;
    u16*   pf2s   = (u16*)ws;   ws += (size_t)NPTS * 128 * sizeof(u16);   // 128 MB (sorted rows)
    u16*   voxmax = (u16*)ws;   ws += (size_t)NVOX * 128 * sizeof(u16);   // 12.8 MB
    u16*   voxf   = (u16*)ws;   ws += (size_t)NVOX * 128 * sizeof(u16);   // 12.8 MB
    float* vox2   = (float*)ws; ws += (size_t)NVOX * 256 * sizeof(float); // 51.2 MB
    u16*   w3f    = (u16*)ws;   ws += 65536 * sizeof(u16);
    u16*   w4f    = (u16*)ws;   ws += 65536 * sizeof(u16);
    u16*   wv1f   = (u16*)ws;   ws += 16384 * sizeof(u16);
    u16*   wv2f   = (u16*)ws;   ws += 65536 * sizeof(u16);
    u16*   wcatf  = (u16*)ws;   ws += 8192 * sizeof(u16);
    u16*   wattf  = (u16*)ws;   ws += 4096 * sizeof(u16);
    int*   hcnt   = (int*)ws;   ws += (size_t)NVOX * sizeof(int);
    int*   start  = (int*)ws;   ws += (size_t)NVOX * sizeof(int);
    int*   cur    = (int*)ws;   ws += (size_t)NVOX * sizeof(int);
    int*   bsum   = (int*)ws;   ws += (size_t)NBLK * sizeof(int);
    int*   boff   = (int*)ws;   ws += (size_t)NBLK * sizeof(int);
    int*   rank   = (int*)ws;   ws += (size_t)NPTS * sizeof(int);
    int*   svid   = (int*)ws;   ws += (size_t)NPTS * sizeof(int);

    hipMemsetAsync(hcnt, 0, (size_t)NVOX * sizeof(int), stream);
    hipMemsetAsync(vox2, 0, (size_t)NVOX * 256 * sizeof(float), stream);

    k_wtransform<<<256, 256, 0, stream>>>(w3, w3f, 256, 256);
    k_wtransform<<<256, 256, 0, stream>>>(w4, w4f, 256, 256);
    k_wtransform<<<64,  256, 0, stream>>>(wv1, wv1f, 128, 128);
    k_wtransform<<<256, 256, 0, stream>>>(wv2, wv2f, 256, 256);
    k_wcat<<<32, 256, 0, stream>>>(w2x, w2r, wcatf);
    k_watt<<<16, 256, 0, stream>>>(wax, war, wattf);

    k_hist<<<(NPTS + 255) / 256, 256, 0, stream>>>(idx, hcnt);
    k_scan1<<<NBLK, 256, 0, stream>>>(hcnt, bsum);
    k_scan2<<<1, 256, 0, stream>>>(bsum, boff);
    k_scan3<<<NBLK, 256, 0, stream>>>(hcnt, boff, start, cur);
    k_scatter<<<(NPTS + 255) / 256, 256, 0, stream>>>(idx, cur, rank, svid);

    k_pointfeat<<<(NPTS + 63) / 64, 256, 0, stream>>>(
        inp, rank, w1x, b1x, w1r, b1r, wcatf, b2x, b2r, wattf, bax, bar, pf2s);

    k_segmax<<<(NVOX + 3) / 4, 256, 0, stream>>>(pf2s, start, hcnt, voxmax);

    k_gemm_relu<128, 128, true, true><<<(NVOX + 63) / 64, 256, 0, stream>>>(
        (const void*)voxmax, wv1f, bv1, (void*)voxf, NVOX);

    k_pointmlp<<<(NPTS + 63) / 64, 256, 0, stream>>>(
        voxf, pf2s, svid, w3f, b3, w4f, b4, vox2);

    k_gemm_relu<256, 256, false, false><<<(NVOX + 63) / 64, 256, 0, stream>>>(
        (const void*)vox2, wv2f, bv2, (void*)out, NVOX);
}

// Round 5
// 493.693 us; speedup vs baseline: 4.5132x; 1.0615x over previous
//
#include <hip/hip_runtime.h>

#define NPTS 500000
#define NVOX 50000
#define NBLK 196   // ceil(NVOX/256)

typedef unsigned short u16;
typedef unsigned int u32;
typedef __attribute__((ext_vector_type(8))) short short8;
typedef __attribute__((ext_vector_type(4))) float floatx4;
typedef __attribute__((ext_vector_type(4))) unsigned int uintx4;
typedef __attribute__((ext_vector_type(2))) unsigned int uintx2;

__device__ __forceinline__ u16 f2bf(float f) {
    u32 u = __float_as_uint(f);
    u = u + 0x7fffu + ((u >> 16) & 1u);   // RNE
    return (u16)(u >> 16);
}

// ---- K0: swizzle fp32 weight (K x N, row-major) into fragment-contiguous bf16 ----
// Same pack serves as B-operand of W and A-operand of W^T:
//   Wf[((kk*4+q)*N + n)*8 + j] = W[(kk*32+q*8+j)*N + n]
__global__ void k_wtransform(const float* __restrict__ W, u16* __restrict__ Wf, int K, int N) {
    int t = blockIdx.x * 256 + threadIdx.x;
    if (t >= K * N) return;
    int k = t / N, n = t - k * N;
    int kk = k >> 5, q = (k >> 3) & 3, j = k & 7;
    Wf[((size_t)((kk * 4 + q) * N + n) << 3) + j] = f2bf(W[t]);
}

// block-diag [[w2x,0],[0,w2r]] (128x64), swizzled (B-operand)
__global__ void k_wcat(const float* __restrict__ w2x, const float* __restrict__ w2r, u16* __restrict__ wcatf) {
    int t = blockIdx.x * 256 + threadIdx.x;
    if (t >= 128 * 64) return;
    int k = t >> 6, n = t & 63;
    float v;
    if (k < 64) v = (n < 32) ? w2x[k * 32 + n] : 0.f;
    else        v = (n >= 32) ? w2r[(k - 64) * 32 + (n - 32)] : 0.f;
    int kk = k >> 5, q = (k >> 3) & 3, j = k & 7;
    wcatf[((size_t)((kk * 4 + q) * 64 + n) << 3) + j] = f2bf(v);
}

// [wax | war] (64x64), swizzled (B-operand)
__global__ void k_watt(const float* __restrict__ wax, const float* __restrict__ war, u16* __restrict__ wattf) {
    int t = blockIdx.x * 256 + threadIdx.x;
    if (t >= 64 * 64) return;
    int k = t >> 6, n = t & 63;
    float v = (n < 32) ? wax[k * 32 + n] : war[k * 32 + (n - 32)];
    int kk = k >> 5, q = (k >> 3) & 3, j = k & 7;
    wattf[((size_t)((kk * 4 + q) * 64 + n) << 3) + j] = f2bf(v);
}

// ---- CSR build: histogram -> 3-phase parallel scan -> scatter (sptid + sorted vid) ----
__global__ void k_hist(const int* __restrict__ idx, int* __restrict__ hcnt) {
    int i = blockIdx.x * 256 + threadIdx.x;
    if (i < NPTS) atomicAdd(&hcnt[idx[i]], 1);
}

__global__ __launch_bounds__(256) void k_scan1(const int* __restrict__ hcnt, int* __restrict__ bsum) {
    __shared__ int wsum[4];
    int t = threadIdx.x;
    int i = blockIdx.x * 256 + t;
    int c = (i < NVOX) ? hcnt[i] : 0;
    #pragma unroll
    for (int d = 32; d >= 1; d >>= 1) c += __shfl_xor(c, d, 64);
    if ((t & 63) == 0) wsum[t >> 6] = c;
    __syncthreads();
    if (t == 0) bsum[blockIdx.x] = wsum[0] + wsum[1] + wsum[2] + wsum[3];
}

__global__ __launch_bounds__(256) void k_scan2(const int* __restrict__ bsum, int* __restrict__ boff) {
    __shared__ int wsum[4];
    int t = threadIdx.x, lane = t & 63, w = t >> 6;
    int c = (t < NBLK) ? bsum[t] : 0;
    int v = c;
    #pragma unroll
    for (int d = 1; d < 64; d <<= 1) {
        int o = __shfl_up(v, d, 64);
        if (lane >= d) v += o;
    }
    if (lane == 63) wsum[w] = v;
    __syncthreads();
    int wo = 0;
    #pragma unroll
    for (int k = 0; k < 4; k++) if (k < w) wo += wsum[k];
    if (t < NBLK) boff[t] = wo + v - c;
}

__global__ __launch_bounds__(256) void k_scan3(const int* __restrict__ hcnt, const int* __restrict__ boff,
                                               int* __restrict__ cur) {
    __shared__ int wsum[4];
    int t = threadIdx.x, lane = t & 63, w = t >> 6;
    int i = blockIdx.x * 256 + t;
    int c = (i < NVOX) ? hcnt[i] : 0;
    int v = c;
    #pragma unroll
    for (int d = 1; d < 64; d <<= 1) {
        int o = __shfl_up(v, d, 64);
        if (lane >= d) v += o;
    }
    if (lane == 63) wsum[w] = v;
    __syncthreads();
    int wo = 0;
    #pragma unroll
    for (int k = 0; k < 4; k++) if (k < w) wo += wsum[k];
    if (i < NVOX) cur[i] = boff[blockIdx.x] + wo + v - c;
}

__global__ void k_scatter(const int* __restrict__ idx, int* __restrict__ cur,
                          int* __restrict__ sptid, int* __restrict__ svid) {
    int i = blockIdx.x * 256 + threadIdx.x;
    if (i < NPTS) {
        int v = idx[i];
        int pos = atomicAdd(&cur[v], 1);
        sptid[pos] = i;
        svid[pos] = v;
    }
}

// ---- K1: sorted-order MFMA point encoder + fused pf2 segment-max -> voxmax (fp32) ----
__global__ __launch_bounds__(256) void k_pointfeat(
    const float* __restrict__ inp, const int* __restrict__ sptid, const int* __restrict__ svid,
    const float* __restrict__ w1x, const float* __restrict__ b1x,
    const float* __restrict__ w1r, const float* __restrict__ b1r,
    const u16* __restrict__ wcatf, const float* __restrict__ b2x, const float* __restrict__ b2r,
    const u16* __restrict__ wattf, const float* __restrict__ bax, const float* __restrict__ bar,
    u16* __restrict__ pf2s, float* __restrict__ voxmax)
{
    __shared__ u16 hbuf[64 * 136];   // h tile (64x128 +8 pad); reused for pf2 out-tile
    __shared__ u16 cbuf[64 * 72];    // comb tile (64x64 +8 pad)
    __shared__ float wl[512];        // w1x(192) b1x(64) w1r(192) b1r(64)
    __shared__ int lvid[64];
    int t = threadIdx.x;
    int i0 = blockIdx.x * 64;
    int mcnt = NPTS - i0; if (mcnt > 64) mcnt = 64;
    for (int s = t; s < 512; s += 256) {
        float v;
        if (s < 192)      v = w1x[s];
        else if (s < 256) v = b1x[s - 192];
        else if (s < 448) v = w1r[s - 256];
        else              v = b1r[s - 448];
        wl[s] = v;
    }
    if (t < 64) lvid[t] = (t < mcnt) ? svid[i0 + t] : -1;
    __syncthreads();
    {   // layer 1: K=3 on VALU, 4 threads/point each produce 16 h_x + 16 h_r cols
        int m = t >> 2, c = t & 3;
        float x0 = 0, x1 = 0, x2 = 0, r0 = 0, r1 = 0, r2 = 0;
        if (m < mcnt) {
            const float* p = inp + (size_t)sptid[i0 + m] * 6;
            x0 = p[0]; x1 = p[1]; x2 = p[2]; r0 = p[3]; r1 = p[4]; r2 = p[5];
        }
        u16* hb = &hbuf[m * 136 + c * 16];
        #pragma unroll
        for (int jp = 0; jp < 8; jp++) {
            int c0 = c * 16 + 2 * jp, c1 = c0 + 1;
            float hx0 = fmaxf(wl[192 + c0] + x0 * wl[c0] + x1 * wl[64 + c0] + x2 * wl[128 + c0], 0.f);
            float hx1 = fmaxf(wl[192 + c1] + x0 * wl[c1] + x1 * wl[64 + c1] + x2 * wl[128 + c1], 0.f);
            float hr0 = fmaxf(wl[448 + c0] + r0 * wl[256 + c0] + r1 * wl[320 + c0] + r2 * wl[384 + c0], 0.f);
            float hr1 = fmaxf(wl[448 + c1] + r0 * wl[256 + c1] + r1 * wl[320 + c1] + r2 * wl[384 + c1], 0.f);
            *(u32*)(hb + 2 * jp)      = (u32)f2bf(hx0) | ((u32)f2bf(hx1) << 16);
            *(u32*)(hb + 64 + 2 * jp) = (u32)f2bf(hr0) | ((u32)f2bf(hr1) << 16);
        }
    }
    __syncthreads();
    int wave = t >> 6, l = t & 63, q = l >> 4, lm = l & 15;
    int n = wave * 16 + lm;    // each wave owns 16 output cols
    // GEMM1: comb(64x64) = h(64x128) @ wcat(128x64)
    floatx4 acc[4];
    #pragma unroll
    for (int a = 0; a < 4; a++) acc[a] = (floatx4){0.f, 0.f, 0.f, 0.f};
    #pragma unroll
    for (int kk = 0; kk < 4; kk++) {
        short8 bfrag = *(const short8*)&wcatf[(size_t)((kk * 4 + q) * 64 + n) << 3];
        #pragma unroll
        for (int tm = 0; tm < 4; tm++) {
            short8 afrag = *(const short8*)&hbuf[(tm * 16 + lm) * 136 + kk * 32 + q * 8];
            acc[tm] = __builtin_amdgcn_mfma_f32_16x16x32_bf16(afrag, bfrag, acc[tm], 0, 0, 0);
        }
    }
    float bv = (n < 32) ? b2x[n] : b2r[n - 32];
    float comb_keep[4][4];
    #pragma unroll
    for (int tm = 0; tm < 4; tm++)
        #pragma unroll
        for (int r = 0; r < 4; r++) {
            float v = fmaxf(acc[tm][r] + bv, 0.f);
            comb_keep[tm][r] = v;
            int m = tm * 16 + q * 4 + r;     // C/D: row = quad*4+reg, col = lane&15
            cbuf[m * 72 + n] = f2bf(v);
        }
    __syncthreads();
    // GEMM2: att(64x64) = comb @ watt; same C-layout as comb -> register-local gating
    floatx4 acc2[4];
    #pragma unroll
    for (int a = 0; a < 4; a++) acc2[a] = (floatx4){0.f, 0.f, 0.f, 0.f};
    #pragma unroll
    for (int kk = 0; kk < 2; kk++) {
        short8 bfrag = *(const short8*)&wattf[(size_t)((kk * 4 + q) * 64 + n) << 3];
        #pragma unroll
        for (int tm = 0; tm < 4; tm++) {
            short8 afrag = *(const short8*)&cbuf[(tm * 16 + lm) * 72 + kk * 32 + q * 8];
            acc2[tm] = __builtin_amdgcn_mfma_f32_16x16x32_bf16(afrag, bfrag, acc2[tm], 0, 0, 0);
        }
    }
    float bv2 = (n < 32) ? bax[n] : bar[n - 32];
    int pp = (n < 32) ? n : 32 + n;   // pf2 col of plain value; gated at pp+32
    #pragma unroll
    for (int tm = 0; tm < 4; tm++)
        #pragma unroll
        for (int r = 0; r < 4; r++) {
            float att = acc2[tm][r] + bv2;
            float sg = 1.f / (1.f + __expf(-att));
            float plain = comb_keep[tm][r];
            float gated = plain * sg;
            int m = tm * 16 + q * 4 + r;
            hbuf[m * 136 + pp] = f2bf(plain);
            hbuf[m * 136 + pp + 32] = f2bf(gated);
        }
    __syncthreads();
    {   // coalesced pf2s store (sorted rows): 4 threads/row x 64B
        int row = t >> 2, seg = t & 3;
        if (row < mcnt) {
            const u16* src = &hbuf[row * 136 + seg * 32];
            u16* dst = pf2s + (size_t)(i0 + row) * 128 + seg * 32;
            *(uintx4*)dst = *(const uintx4*)src;
            *(uintx4*)(dst + 8) = *(const uintx4*)(src + 8);
        }
    }
    {   // fused segment-max over sorted vid runs -> voxmax fp32 (values >= 0, int cmp)
        int c2 = t & 63;           // u32 col-pair (cols 2c2, 2c2+1) of 128
        int h = t >> 6;            // row quarter (16 rows)
        int r0 = h * 16;
        int r1 = r0 + 16; if (r1 > mcnt) r1 = mcnt;
        u32 mlo = 0, mhi = 0;
        int pvid = -1;
        for (int r = r0; r < r1; r++) {
            int vid = lvid[r];
            if (vid != pvid) {
                if (pvid >= 0) {
                    int* addr = (int*)(voxmax + (size_t)pvid * 128 + 2 * c2);
                    if (mlo) atomicMax(addr, (int)(mlo << 16));
                    if (mhi) atomicMax(addr + 1, (int)(mhi << 16));
                }
                pvid = vid; mlo = 0; mhi = 0;
            }
            u32 u = *(const u32*)&hbuf[r * 136 + 2 * c2];
            u32 lo = u & 0xffffu, hi = u >> 16;
            mlo = lo > mlo ? lo : mlo;
            mhi = hi > mhi ? hi : mhi;
        }
        if (pvid >= 0) {
            int* addr = (int*)(voxmax + (size_t)pvid * 128 + 2 * c2);
            if (mlo) atomicMax(addr, (int)(mlo << 16));
            if (mhi) atomicMax(addr + 1, (int)(mhi << 16));
        }
    }
}

// ---- generic MFMA GEMM: out = relu(A @ W + bias); A fp32 or bf16; W pre-swizzled bf16 ----
template<int K, int N, bool ABF16, bool OUT_BF16>
__global__ __launch_bounds__(256) void k_gemm_relu(
    const void* __restrict__ Ap, const u16* __restrict__ Wf,
    const float* __restrict__ bias, void* __restrict__ outp, int M)
{
    constexpr int STRIDE = K + 8;
    constexpr int TN = N / 64;
    constexpr int KSTEPS = K / 32;
    constexpr int CW = K / 4;
    __shared__ u16 lds[64 * STRIDE];
    int i0 = blockIdx.x * 64;
    int mcnt = M - i0; if (mcnt > 64) mcnt = 64;
    int t = threadIdx.x;
    {
        int row = t >> 2, cseg = t & 3;
        u16* dst = &lds[row * STRIDE + cseg * CW];
        if (row < mcnt) {
            if (ABF16) {
                const u16* src = (const u16*)Ap + (size_t)(i0 + row) * K + cseg * CW;
                #pragma unroll
                for (int c = 0; c < CW / 8; c++)
                    *(uintx4*)(dst + c * 8) = *(const uintx4*)(src + c * 8);
            } else {
                const float* src = (const float*)Ap + (size_t)(i0 + row) * K + cseg * CW;
                #pragma unroll
                for (int c = 0; c < CW / 8; c++) {
                    float4 v0 = *(const float4*)(src + c * 8);
                    float4 v1 = *(const float4*)(src + c * 8 + 4);
                    short8 rr;
                    rr[0] = f2bf(v0.x); rr[1] = f2bf(v0.y); rr[2] = f2bf(v0.z); rr[3] = f2bf(v0.w);
                    rr[4] = f2bf(v1.x); rr[5] = f2bf(v1.y); rr[6] = f2bf(v1.z); rr[7] = f2bf(v1.w);
                    *(short8*)(dst + c * 8) = rr;
                }
            }
        } else {
            short8 z = {0, 0, 0, 0, 0, 0, 0, 0};
            #pragma unroll
            for (int c = 0; c < CW / 8; c++) *(short8*)(dst + c * 8) = z;
        }
    }
    __syncthreads();
    int wave = t >> 6, l = t & 63;
    int q = l >> 4, lm = l & 15;
    int wn0 = wave * (N / 4);
    floatx4 acc[4][TN];
    #pragma unroll
    for (int a = 0; a < 4; a++)
        #pragma unroll
        for (int b = 0; b < TN; b++) acc[a][b] = (floatx4){0.f, 0.f, 0.f, 0.f};
    #pragma unroll
    for (int kk = 0; kk < KSTEPS; kk++) {
        short8 afrag[4], bfrag[TN];
        #pragma unroll
        for (int tm = 0; tm < 4; tm++)
            afrag[tm] = *(const short8*)&lds[(tm * 16 + lm) * STRIDE + kk * 32 + q * 8];
        #pragma unroll
        for (int tn = 0; tn < TN; tn++)
            bfrag[tn] = *(const short8*)&Wf[(size_t)((kk * 4 + q) * N + wn0 + tn * 16 + lm) * 8];
        #pragma unroll
        for (int tm = 0; tm < 4; tm++)
            #pragma unroll
            for (int tn = 0; tn < TN; tn++)
                acc[tm][tn] = __builtin_amdgcn_mfma_f32_16x16x32_bf16(afrag[tm], bfrag[tn], acc[tm][tn], 0, 0, 0);
    }
    #pragma unroll
    for (int tm = 0; tm < 4; tm++)
        #pragma unroll
        for (int tn = 0; tn < TN; tn++) {
            int n = wn0 + tn * 16 + lm;
            float bv = bias[n];
            #pragma unroll
            for (int r = 0; r < 4; r++) {
                int m = tm * 16 + q * 4 + r;
                if (m < mcnt) {
                    float v = fmaxf(acc[tm][tn][r] + bv, 0.f);
                    if (OUT_BF16) ((u16*)outp)[(size_t)(i0 + m) * N + n] = f2bf(v);
                    else          ((float*)outp)[(size_t)(i0 + m) * N + n] = v;
                }
            }
        }
}

// ---- K3: sorted fused point MLP (swapped-operand MFMA) + in-LDS segmented max -> vox2 ----
// Both GEMMs computed transposed: D = W^T @ Act^T, weights are A-operand (same pack),
// activations are B-operand read row-major from LDS. C-layout reg index then runs along
// the column dim -> packed b64 epilogue writes into the row-major tile.
__global__ __launch_bounds__(256) void k_pointmlp(
    const u16* __restrict__ voxf, const u16* __restrict__ pf2s, const int* __restrict__ svid,
    const u16* __restrict__ w3f, const float* __restrict__ b3,
    const u16* __restrict__ w4f, const float* __restrict__ b4,
    float* __restrict__ vox2)
{
    constexpr int STRIDE = 264;
    __shared__ u16 lds[64 * STRIDE];
    __shared__ int lvid[64];
    __shared__ float bl[512];   // b3(256) | b4(256)
    int i0 = blockIdx.x * 64;
    int mcnt = NPTS - i0; if (mcnt > 64) mcnt = 64;
    int t = threadIdx.x;
    if (t < 64) lvid[t] = (t < mcnt) ? svid[i0 + t] : -1;
    for (int s = t; s < 512; s += 256) bl[s] = (s < 256) ? b3[s] : b4[s - 256];
    {
        int row = t >> 2, cseg = t & 3;       // 4 threads/row, 64 bf16 each
        u16* dst = &lds[row * STRIDE + cseg * 64];
        if (row < mcnt) {
            const u16* src;
            if (cseg < 2) src = voxf + (size_t)svid[i0 + row] * 128 + cseg * 64;     // pg half (sorted: locality)
            else          src = pf2s + (size_t)(i0 + row) * 128 + (cseg - 2) * 64;   // pf2 half (coalesced)
            #pragma unroll
            for (int c = 0; c < 8; c++)
                *(uintx4*)(dst + c * 8) = *(const uintx4*)(src + c * 8);
        } else {
            uintx4 z = {0, 0, 0, 0};
            #pragma unroll
            for (int c = 0; c < 8; c++) *(uintx4*)(dst + c * 8) = z;
        }
    }
    __syncthreads();
    int wave = t >> 6, l = t & 63;
    int q = l >> 4, lm = l & 15;
    int wm0 = wave * 64;     // wave's 64-wide output-column stripe
    floatx4 acc[4][4];
    #pragma unroll
    for (int a = 0; a < 4; a++)
        #pragma unroll
        for (int b = 0; b < 4; b++) acc[a][b] = (floatx4){0.f, 0.f, 0.f, 0.f};
    #pragma unroll
    for (int kk = 0; kk < 8; kk++) {
        short8 wfrag[4], bfrag[4];
        #pragma unroll
        for (int tm = 0; tm < 4; tm++)
            wfrag[tm] = *(const short8*)&w3f[(size_t)((kk * 4 + q) * 256 + wm0 + tm * 16 + lm) * 8];
        #pragma unroll
        for (int tn = 0; tn < 4; tn++)
            bfrag[tn] = *(const short8*)&lds[(tn * 16 + lm) * STRIDE + kk * 32 + q * 8];
        #pragma unroll
        for (int tm = 0; tm < 4; tm++)
            #pragma unroll
            for (int tn = 0; tn < 4; tn++)
                acc[tm][tn] = __builtin_amdgcn_mfma_f32_16x16x32_bf16(wfrag[tm], bfrag[tn], acc[tm][tn], 0, 0, 0);
    }
    __syncthreads();
    // H = relu(H^T acc + b3) -> LDS row-major, packed b64 (4 consecutive cols per frag)
    #pragma unroll
    for (int tm = 0; tm < 4; tm++) {
        float4 bq = *(const float4*)&bl[wm0 + tm * 16 + 4 * q];
        #pragma unroll
        for (int tn = 0; tn < 4; tn++) {
            u32 lo = (u32)f2bf(fmaxf(acc[tm][tn][0] + bq.x, 0.f)) | ((u32)f2bf(fmaxf(acc[tm][tn][1] + bq.y, 0.f)) << 16);
            u32 hi = (u32)f2bf(fmaxf(acc[tm][tn][2] + bq.z, 0.f)) | ((u32)f2bf(fmaxf(acc[tm][tn][3] + bq.w, 0.f)) << 16);
            *(uintx2*)&lds[(tn * 16 + lm) * STRIDE + wm0 + tm * 16 + 4 * q] = (uintx2){lo, hi};
        }
    }
    __syncthreads();
    floatx4 acc2[4][4];
    #pragma unroll
    for (int a = 0; a < 4; a++)
        #pragma unroll
        for (int b = 0; b < 4; b++) acc2[a][b] = (floatx4){0.f, 0.f, 0.f, 0.f};
    #pragma unroll
    for (int kk = 0; kk < 8; kk++) {
        short8 wfrag[4], bfrag[4];
        #pragma unroll
        for (int tm = 0; tm < 4; tm++)
            wfrag[tm] = *(const short8*)&w4f[(size_t)((kk * 4 + q) * 256 + wm0 + tm * 16 + lm) * 8];
        #pragma unroll
        for (int tn = 0; tn < 4; tn++)
            bfrag[tn] = *(const short8*)&lds[(tn * 16 + lm) * STRIDE + kk * 32 + q * 8];
        #pragma unroll
        for (int tm = 0; tm < 4; tm++)
            #pragma unroll
            for (int tn = 0; tn < 4; tn++)
                acc2[tm][tn] = __builtin_amdgcn_mfma_f32_16x16x32_bf16(wfrag[tm], bfrag[tn], acc2[tm][tn], 0, 0, 0);
    }
    __syncthreads();   // all waves done reading H before overwrite
    // pf5 = relu(acc2 + b4) -> LDS row-major, packed b64
    #pragma unroll
    for (int tm = 0; tm < 4; tm++) {
        float4 bq = *(const float4*)&bl[256 + wm0 + tm * 16 + 4 * q];
        #pragma unroll
        for (int tn = 0; tn < 4; tn++) {
            u32 lo = (u32)f2bf(fmaxf(acc2[tm][tn][0] + bq.x, 0.f)) | ((u32)f2bf(fmaxf(acc2[tm][tn][1] + bq.y, 0.f)) << 16);
            u32 hi = (u32)f2bf(fmaxf(acc2[tm][tn][2] + bq.z, 0.f)) | ((u32)f2bf(fmaxf(acc2[tm][tn][3] + bq.w, 0.f)) << 16);
            *(uintx2*)&lds[(tn * 16 + lm) * STRIDE + wm0 + tm * 16 + 4 * q] = (uintx2){lo, hi};
        }
    }
    __syncthreads();
    // segmented max over sorted vid runs: thread owns u32 col-pair x 32 rows
    {
        int c2 = t & 127;          // u32 column (cols 2c2, 2c2+1)
        int h = t >> 7;            // row half
        int r0 = h * 32;
        int r1 = r0 + 32; if (r1 > mcnt) r1 = mcnt;
        u32 mlo = 0, mhi = 0;
        int pvid = -1;
        for (int r = r0; r < r1; r++) {
            int vid = lvid[r];
            if (vid != pvid) {
                if (pvid >= 0) {
                    int* addr = (int*)(vox2 + (size_t)pvid * 256 + 2 * c2);
                    if (mlo) atomicMax(addr, (int)(mlo << 16));
                    if (mhi) atomicMax(addr + 1, (int)(mhi << 16));
                }
                pvid = vid; mlo = 0; mhi = 0;
            }
            u32 u = *(const u32*)&lds[r * STRIDE + 2 * c2];
            u32 lo = u & 0xffffu, hi = u >> 16;
            mlo = lo > mlo ? lo : mlo;
            mhi = hi > mhi ? hi : mhi;
        }
        if (pvid >= 0) {
            int* addr = (int*)(vox2 + (size_t)pvid * 256 + 2 * c2);
            if (mlo) atomicMax(addr, (int)(mlo << 16));
            if (mhi) atomicMax(addr + 1, (int)(mhi << 16));
        }
    }
}

extern "C" void kernel_launch(void* const* d_in, const int* in_sizes, int n_in,
                              void* d_out, int out_size, void* d_ws, size_t ws_size,
                              hipStream_t stream) {
    const float* inp = (const float*)d_in[0];
    const int*   idx = (const int*)d_in[1];
    const float* w1x = (const float*)d_in[3];  const float* b1x = (const float*)d_in[4];
    const float* w2x = (const float*)d_in[5];  const float* b2x = (const float*)d_in[6];
    const float* w1r = (const float*)d_in[7];  const float* b1r = (const float*)d_in[8];
    const float* w2r = (const float*)d_in[9];  const float* b2r = (const float*)d_in[10];
    const float* wax = (const float*)d_in[11]; const float* bax = (const float*)d_in[12];
    const float* war = (const float*)d_in[13]; const float* bar = (const float*)d_in[14];
    const float* wv1 = (const float*)d_in[15]; const float* bv1 = (const float*)d_in[16];
    const float* w3  = (const float*)d_in[17]; const float* b3  = (const float*)d_in[18];
    const float* w4  = (const float*)d_in[19]; const float* b4  = (const float*)d_in[20];
    const float* wv2 = (const float*)d_in[21]; const float* bv2 = (const float*)d_in[22];
    float* out = (float*)d_out;

    char* ws = (char*)d_ws;
    u16*   pf2s   = (u16*)ws;   ws += (size_t)NPTS * 128 * sizeof(u16);   // 128 MB (sorted rows)
    float* voxmax = (float*)ws; ws += (size_t)NVOX * 128 * sizeof(float); // 25.6 MB
    u16*   voxf   = (u16*)ws;   ws += (size_t)NVOX * 128 * sizeof(u16);   // 12.8 MB
    float* vox2   = (float*)ws; ws += (size_t)NVOX * 256 * sizeof(float); // 51.2 MB
    u16*   w3f    = (u16*)ws;   ws += 65536 * sizeof(u16);
    u16*   w4f    = (u16*)ws;   ws += 65536 * sizeof(u16);
    u16*   wv1f   = (u16*)ws;   ws += 16384 * sizeof(u16);
    u16*   wv2f   = (u16*)ws;   ws += 65536 * sizeof(u16);
    u16*   wcatf  = (u16*)ws;   ws += 8192 * sizeof(u16);
    u16*   wattf  = (u16*)ws;   ws += 4096 * sizeof(u16);
    int*   hcnt   = (int*)ws;   ws += (size_t)NVOX * sizeof(int);
    int*   cur    = (int*)ws;   ws += (size_t)NVOX * sizeof(int);
    int*   bsum   = (int*)ws;   ws += (size_t)NBLK * sizeof(int);
    int*   boff   = (int*)ws;   ws += (size_t)NBLK * sizeof(int);
    int*   sptid  = (int*)ws;   ws += (size_t)NPTS * sizeof(int);
    int*   svid   = (int*)ws;   ws += (size_t)NPTS * sizeof(int);

    hipMemsetAsync(hcnt, 0, (size_t)NVOX * sizeof(int), stream);
    hipMemsetAsync(voxmax, 0, (size_t)NVOX * 128 * sizeof(float), stream);
    hipMemsetAsync(vox2, 0, (size_t)NVOX * 256 * sizeof(float), stream);

    k_wtransform<<<256, 256, 0, stream>>>(w3, w3f, 256, 256);
    k_wtransform<<<256, 256, 0, stream>>>(w4, w4f, 256, 256);
    k_wtransform<<<64,  256, 0, stream>>>(wv1, wv1f, 128, 128);
    k_wtransform<<<256, 256, 0, stream>>>(wv2, wv2f, 256, 256);
    k_wcat<<<32, 256, 0, stream>>>(w2x, w2r, wcatf);
    k_watt<<<16, 256, 0, stream>>>(wax, war, wattf);

    k_hist<<<(NPTS + 255) / 256, 256, 0, stream>>>(idx, hcnt);
    k_scan1<<<NBLK, 256, 0, stream>>>(hcnt, bsum);
    k_scan2<<<1, 256, 0, stream>>>(bsum, boff);
    k_scan3<<<NBLK, 256, 0, stream>>>(hcnt, boff, cur);
    k_scatter<<<(NPTS + 255) / 256, 256, 0, stream>>>(idx, cur, sptid, svid);

    k_pointfeat<<<(NPTS + 63) / 64, 256, 0, stream>>>(
        inp, sptid, svid, w1x, b1x, w1r, b1r, wcatf, b2x, b2r, wattf, bax, bar, pf2s, voxmax);

    k_gemm_relu<128, 128, false, true><<<(NVOX + 63) / 64, 256, 0, stream>>>(
        (const void*)voxmax, wv1f, bv1, (void*)voxf, NVOX);

    k_pointmlp<<<(NPTS + 63) / 64, 256, 0, stream>>>(
        voxf, pf2s, svid, w3f, b3, w4f, b4, vox2);

    k_gemm_relu<256, 256, false, false><<<(NVOX + 63) / 64, 256, 0, stream>>>(
        (const void*)vox2, wv2f, bv2, (void*)out, NVOX);
}